// Round 1
// baseline (1897.974 us; speedup 1.0000x reference)
//
#include <hip/hip_runtime.h>
#include <cstdint>
#include <cstddef>

typedef unsigned int   u32;
typedef unsigned short u16;

__device__ __forceinline__ float bf2f(u32 bits16) { return __uint_as_float(bits16 << 16); }
__device__ __forceinline__ u16 f2bf(float f) {
  u32 u = __float_as_uint(f);
  u = u + 0x7FFFu + ((u >> 16) & 1u);   // round-to-nearest-even
  return (u16)(u >> 16);
}
__device__ __forceinline__ float fast_silu(float x) { return __fdividef(x, 1.0f + __expf(-x)); }
__device__ __forceinline__ float fast_tanh(float z) { return 1.0f - __fdividef(2.0f, 1.0f + __expf(2.0f * z)); }

// ---- edge_index may be int32 or int64 in device memory; detect at runtime ----
__global__ void k_detect(const int* eidx, int* flag, int E) {
  __shared__ int zc;
  if (threadIdx.x == 0) zc = 0;
  __syncthreads();
  int n = (E < 1024) ? E : 1024;
  int local = 0;
  for (int i = threadIdx.x; i < n; i += 256) {
    if (eidx[2 * i + 1] == 0) local++;   // high words if int64 (all 0), else row values (rarely 0)
  }
  atomicAdd(&zc, local);
  __syncthreads();
  if (threadIdx.x == 0) *flag = (zc >= (n >> 1)) ? 1 : 0;
}

__device__ __forceinline__ int load_idx(const int* eidx, int is64, long long pos) {
  if (is64) return (int)(((const long long*)eidx)[pos]);
  return eidx[pos];
}

// ---- weight prep: transposed copies + Wc = Wvl_l @ Wvv, bc = Wvl_l@bvv + bvl ----
__global__ void k_prep_weights(const float* Wss, const float* Wvs, const float* Wsl,
                               const float* Wsv, const float* Wvv, const float* Wvl,
                               const float* bvv, const float* bvl,
                               float* WT_sc, float* WT_v, float* WslT, float* WcT,
                               float* WvlrT, float* bc) {
  int tid = threadIdx.x;
  for (int o = tid; o < 64 * 256; o += 256) {        // WT_sc[k*256+j]
    int k = o >> 8, j = o & 255;
    float v;
    if (j < 64)       v = Wss[j * 128 + k];                 // a_i
    else if (j < 128) v = Wss[(j - 64) * 128 + 64 + k];     // a_j
    else if (j < 192) v = Wsv[(j - 128) * 128 + k];         // c_i
    else              v = Wsv[(j - 192) * 128 + 64 + k];    // c_j
    WT_sc[o] = v;
  }
  for (int o = tid; o < 64 * 128; o += 256) {        // WT_v[k*128+j]
    int k = o >> 7, j = o & 127;
    WT_v[o] = (j < 64) ? Wvs[j * 128 + k] : Wvs[(j - 64) * 128 + 64 + k];
  }
  for (int o = tid; o < 128 * 64; o += 256) {        // WslT[k*64+c] = Wsl[c][k]
    int k = o >> 6, c = o & 63;
    WslT[o] = Wsl[c * 128 + k];
  }
  for (int o = tid; o < 64 * 64; o += 256) {         // WvlrT[k*64+c] = Wvl[c][64+k]
    int k = o >> 6, c = o & 63;
    WvlrT[o] = Wvl[c * 128 + 64 + k];
  }
  for (int o = tid; o < 128 * 64; o += 256) {        // WcT[kk*64+c] = (Wvl_l@Wvv)[c][kk]
    int kk = o >> 6, c = o & 63;
    float s = 0.f;
    for (int m = 0; m < 64; ++m) s += Wvl[c * 128 + m] * Wvv[m * 128 + kk];
    WcT[o] = s;
  }
  if (tid < 64) {
    float s = 0.f;
    for (int m = 0; m < 64; ++m) s += Wvl[tid * 128 + m] * bvv[m];
    bc[tid] = s + bvl[tid];
  }
}

__global__ void k_deg(const int* eidx, const int* flag, const float* attr,
                      float* deg, int* cnt, int E) {
  int e = blockIdx.x * 256 + threadIdx.x;
  if (e >= E) return;
  int is64 = *flag;
  int col = load_idx(eidx, is64, (long long)E + e);
  atomicAdd(&deg[col], attr[e]);
  atomicAdd(&cnt[col], 1);
}

__global__ void k_dis(const float* deg, float* dis, int N) {
  int i = blockIdx.x * 256 + threadIdx.x;
  if (i < N) { float d = deg[i]; dis[i] = (d > 0.f) ? rsqrtf(d) : 0.f; }
}

__global__ void k_scan(const int* cnt, int* rowptr, int* cursor, int N, int E) {
  __shared__ int lds[1024];
  int tid = threadIdx.x;
  int CH = (N + 1023) / 1024;
  int base = tid * CH;
  int s = 0;
  for (int j = 0; j < CH; ++j) { int idx = base + j; if (idx < N) s += cnt[idx]; }
  lds[tid] = s;
  __syncthreads();
  for (int off = 1; off < 1024; off <<= 1) {
    int v = (tid >= off) ? lds[tid - off] : 0;
    __syncthreads();
    lds[tid] += v;
    __syncthreads();
  }
  int pre = (tid == 0) ? 0 : lds[tid - 1];
  for (int j = 0; j < CH; ++j) {
    int idx = base + j;
    if (idx < N) { rowptr[idx] = pre; cursor[idx] = pre; pre += cnt[idx]; }
  }
  if (tid == 0) rowptr[N] = E;
}

// CSR fill: erecA[p]={norm, row, pos_j.x, pos_j.y}, erecB[p]=pos_j.z
__global__ void k_fill(const int* eidx, const int* flag, const float* attr, const float* dis,
                       const float* pos, int* cursor, float4* erecA, float* erecB, int E) {
  int e = blockIdx.x * 256 + threadIdx.x;
  if (e >= E) return;
  int is64 = *flag;
  int r  = load_idx(eidx, is64, e);
  int cl = load_idx(eidx, is64, (long long)E + e);
  float nrm = dis[r] * dis[cl] * attr[e];
  int p = atomicAdd(&cursor[cl], 1);
  erecA[p] = make_float4(nrm, __int_as_float(r), pos[r * 3 + 0], pos[r * 3 + 1]);
  erecB[p] = pos[r * 3 + 2];
}

// node GEMM: [N,64] @ WT[64,256] -> packed bf16 records (a_i,c_i -> rec_i; a_j,c_j -> rec_j)
// rec_i[n]: 320 bf16, lane group c*5: {a_i, c_i, b_i0, b_i1, b_i2}
// rec_j[n]: 512 bf16, lane group c*8: {a_j, c_j, b_j0, b_j1, b_j2, v_j0, v_j1, v_j2}
__global__ void k_gemm_sc(const float* X, const float* WT, u16* rec_i, u16* rec_j, int N) {
  __shared__ float Xs[64 * 68];
  __shared__ float Ws[64 * 68];
  int tid = threadIdx.x;
  int nb = blockIdx.x * 64;
  for (int i = 0; i < 16; ++i) {
    int flat = tid + i * 256;
    int r = flat >> 6, k = flat & 63;
    Xs[k * 68 + r] = (nb + r < N) ? X[(size_t)(nb + r) * 64 + k] : 0.f;
  }
  int ty = tid >> 4, tx = tid & 15;
  int r0 = ty * 4, c0 = tx * 4;
  for (int jt = 0; jt < 4; ++jt) {
    __syncthreads();
    for (int i = 0; i < 16; ++i) {
      int flat = tid + i * 256;
      int k = flat >> 6, c = flat & 63;
      Ws[k * 68 + c] = WT[k * 256 + jt * 64 + c];
    }
    __syncthreads();
    float acc[4][4] = {};
    for (int k = 0; k < 64; ++k) {
      float4 a = *(const float4*)&Xs[k * 68 + r0];
      float4 b = *(const float4*)&Ws[k * 68 + c0];
      acc[0][0] += a.x * b.x; acc[0][1] += a.x * b.y; acc[0][2] += a.x * b.z; acc[0][3] += a.x * b.w;
      acc[1][0] += a.y * b.x; acc[1][1] += a.y * b.y; acc[1][2] += a.y * b.z; acc[1][3] += a.y * b.w;
      acc[2][0] += a.z * b.x; acc[2][1] += a.z * b.y; acc[2][2] += a.z * b.z; acc[2][3] += a.z * b.w;
      acc[3][0] += a.w * b.x; acc[3][1] += a.w * b.y; acc[3][2] += a.w * b.z; acc[3][3] += a.w * b.w;
    }
    for (int ii = 0; ii < 4; ++ii) {
      int n = nb + r0 + ii;
      if (n >= N) continue;
      for (int jj = 0; jj < 4; ++jj) {
        int cc = c0 + jj;
        u16 h = f2bf(acc[ii][jj]);
        if (jt == 0)      rec_i[(size_t)n * 320 + cc * 5 + 0] = h;
        else if (jt == 1) rec_j[(size_t)n * 512 + cc * 8 + 0] = h;
        else if (jt == 2) rec_i[(size_t)n * 320 + cc * 5 + 1] = h;
        else              rec_j[(size_t)n * 512 + cc * 8 + 1] = h;
      }
    }
  }
}

// vector GEMM: [3N,64] @ WT[64,128] -> b_i/b_j slots; also bf16 copy of vector -> v_j slots
__global__ void k_gemm_v(const float* X, const float* WT, u16* rec_i, u16* rec_j, int M) {
  __shared__ float Xs[64 * 68];
  __shared__ float Ws[64 * 68];
  int tid = threadIdx.x;
  int mb = blockIdx.x * 64;
  for (int i = 0; i < 16; ++i) {
    int flat = tid + i * 256;
    int r = flat >> 6, k = flat & 63;
    Xs[k * 68 + r] = (mb + r < M) ? X[(size_t)(mb + r) * 64 + k] : 0.f;
  }
  __syncthreads();
  for (int i = 0; i < 16; ++i) {   // bf16 copy of vector into rec_j slots 5..7
    int flat = tid + i * 256;
    int r = flat >> 6, k = flat & 63;
    int m = mb + r;
    if (m < M) {
      int n = m / 3, d = m - n * 3;
      rec_j[(size_t)n * 512 + k * 8 + 5 + d] = f2bf(Xs[k * 68 + r]);
    }
  }
  int ty = tid >> 4, tx = tid & 15;
  int r0 = ty * 4, c0 = tx * 4;
  for (int jt = 0; jt < 2; ++jt) {
    __syncthreads();
    for (int i = 0; i < 16; ++i) {
      int flat = tid + i * 256;
      int k = flat >> 6, c = flat & 63;
      Ws[k * 68 + c] = WT[k * 128 + jt * 64 + c];
    }
    __syncthreads();
    float acc[4][4] = {};
    for (int k = 0; k < 64; ++k) {
      float4 a = *(const float4*)&Xs[k * 68 + r0];
      float4 b = *(const float4*)&Ws[k * 68 + c0];
      acc[0][0] += a.x * b.x; acc[0][1] += a.x * b.y; acc[0][2] += a.x * b.z; acc[0][3] += a.x * b.w;
      acc[1][0] += a.y * b.x; acc[1][1] += a.y * b.y; acc[1][2] += a.y * b.z; acc[1][3] += a.y * b.w;
      acc[2][0] += a.z * b.x; acc[2][1] += a.z * b.y; acc[2][2] += a.z * b.z; acc[2][3] += a.z * b.w;
      acc[3][0] += a.w * b.x; acc[3][1] += a.w * b.y; acc[3][2] += a.w * b.z; acc[3][3] += a.w * b.w;
    }
    for (int ii = 0; ii < 4; ++ii) {
      int m = mb + r0 + ii;
      if (m >= M) continue;
      int n = m / 3, d = m - n * 3;
      for (int jj = 0; jj < 4; ++jj) {
        int cc = c0 + jj;
        u16 h = f2bf(acc[ii][jj]);
        if (jt == 0) rec_i[(size_t)n * 320 + cc * 5 + 2 + d] = h;
        else         rec_j[(size_t)n * 512 + cc * 8 + 2 + d] = h;
      }
    }
  }
}

// hot kernel: one wave per node, CSR loop over incoming edges, register accumulation
__global__ void k_edges(const u16* rec_i, const u16* rec_j,
                        const float4* erecA, const float* erecB,
                        const int* rowptr, const float* pos,
                        const float* bss, const float* bvs, const float* bsv,
                        float* U, float* tacc, float* gacc, float* wsum, int N) {
  int lane = threadIdx.x & 63;
  int node = blockIdx.x * 4 + (threadIdx.x >> 6);
  if (node >= N) return;
  const u16* ri = rec_i + (size_t)node * 320 + lane * 5;
  float a_i = bf2f(ri[0]);
  float c_i = bf2f(ri[1]);
  float bi0 = bf2f(ri[2]), bi1 = bf2f(ri[3]), bi2 = bf2f(ri[4]);
  float pix = pos[node * 3 + 0], piy = pos[node * 3 + 1], piz = pos[node * 3 + 2];
  float Bss = bss[lane], Bvs = bvs[lane], Bsv = bsv[lane];
  float us = 0, uv = 0, t0 = 0, t1 = 0, t2 = 0, g0 = 0, g1 = 0, g2 = 0, wa = 0;
  int rp = rowptr[node], re = rowptr[node + 1];
  for (int base = rp; base < re; base += 64) {
    int mcount = min(64, re - base);
    float4 eA = make_float4(0.f, 0.f, 0.f, 0.f);
    float  eB = 0.f;
    if (lane < mcount) { eA = erecA[base + lane]; eB = erecB[base + lane]; }
    for (int j = 0; j < mcount; ++j) {
      float nrm = __shfl(eA.x, j);
      int   r   = __float_as_int(__shfl(eA.y, j));
      float pjx = __shfl(eA.z, j), pjy = __shfl(eA.w, j), pjz = __shfl(eB, j);
      uint4 rv = *(const uint4*)(rec_j + (size_t)r * 512 + lane * 8);
      float aj  = bf2f(rv.x & 0xFFFFu);
      float cj  = bf2f(rv.x >> 16);
      float bj0 = bf2f(rv.y & 0xFFFFu);
      float bj1 = bf2f(rv.y >> 16);
      float bj2 = bf2f(rv.z & 0xFFFFu);
      float vj0 = bf2f(rv.z >> 16);
      float vj1 = bf2f(rv.w & 0xFFFFu);
      float vj2 = bf2f(rv.w >> 16);
      float px = pix - pjx, py = piy - pjy, pz = piz - pjz;
      float xs  = a_i + aj + Bss;
      float s2s = fast_silu(xs);
      float y   = (bi0 + bj0 + Bvs) * px + (bi1 + bj1 + Bvs) * py + (bi2 + bj2 + Bvs) * pz;
      float v2s = fast_silu(y);
      float sp  = c_i + cj + Bsv;
      float tv0 = fast_tanh(sp * px), tv1 = fast_tanh(sp * py), tv2 = fast_tanh(sp * pz);
      us += nrm * s2s; uv += nrm * v2s;
      t0 += nrm * tv0; t1 += nrm * tv1; t2 += nrm * tv2;
      g0 += nrm * vj0; g1 += nrm * vj1; g2 += nrm * vj2;
      wa += nrm;
    }
  }
  U[(size_t)node * 128 + lane]      = us;
  U[(size_t)node * 128 + 64 + lane] = uv;
  tacc[(size_t)node * 192 + lane]        = t0;
  tacc[(size_t)node * 192 + 64 + lane]   = t1;
  tacc[(size_t)node * 192 + 128 + lane]  = t2;
  gacc[(size_t)node * 192 + lane]        = g0;
  gacc[(size_t)node * 192 + 64 + lane]   = g1;
  gacc[(size_t)node * 192 + 128 + lane]  = g2;
  if (lane == 0) wsum[node] = wa;
}

// scalar_out = silu(U @ Wsl^T + w*bsl) + scalar
__global__ void k_final_s(const float* U, const float* wsum, const float* WslT,
                          const float* bsl, const float* scalar, float* out, int N) {
  __shared__ float Ush[16 * 128];
  int tid = threadIdx.x, wv = tid >> 6, c = tid & 63;
  int nb = blockIdx.x * 16;
  for (int nn = 0; nn < 4; ++nn) {
    int row = wv * 4 + nn, n = nb + row;
    float u0 = 0.f, u1 = 0.f;
    if (n < N) { u0 = U[(size_t)n * 128 + c]; u1 = U[(size_t)n * 128 + 64 + c]; }
    Ush[row * 128 + c] = u0; Ush[row * 128 + 64 + c] = u1;
  }
  __syncthreads();
  float Bsl = bsl[c];
  float acc[4];
  for (int nn = 0; nn < 4; ++nn) {
    int n = nb + wv * 4 + nn;
    float wl = (n < N) ? wsum[n] : 0.f;
    acc[nn] = wl * Bsl;
  }
  for (int k = 0; k < 128; k += 4) {
    float w0 = WslT[k * 64 + c], w1 = WslT[(k + 1) * 64 + c];
    float w2 = WslT[(k + 2) * 64 + c], w3 = WslT[(k + 3) * 64 + c];
    for (int nn = 0; nn < 4; ++nn) {
      float4 u = *(const float4*)&Ush[(wv * 4 + nn) * 128 + k];
      acc[nn] += u.x * w0 + u.y * w1 + u.z * w2 + u.w * w3;
    }
  }
  for (int nn = 0; nn < 4; ++nn) {
    int n = nb + wv * 4 + nn;
    if (n < N) out[(size_t)n * 64 + c] = fast_silu(acc[nn]) + scalar[(size_t)n * 64 + c];
  }
}

// vector_out = tanh([w*v_i | g] @ Wc^T + t @ Wvl_r^T + w*bc) + vector
__global__ void k_final_v(const float* tacc, const float* gacc, const float* wsum,
                          const float* vector, const float* WcT, const float* WvlrT,
                          const float* bc, float* out_v, int M) {
  __shared__ float Vsh[16 * 192];
  int tid = threadIdx.x, wv = tid >> 6, c = tid & 63;
  int mb = blockIdx.x * 16;
  float wl[4];
  for (int nn = 0; nn < 4; ++nn) {
    int row = wv * 4 + nn, m = mb + row;
    float a = 0.f, b = 0.f, t = 0.f, wn = 0.f;
    if (m < M) {
      wn = wsum[m / 3];
      a = wn * vector[(size_t)m * 64 + c];
      b = gacc[(size_t)m * 64 + c];
      t = tacc[(size_t)m * 64 + c];
    }
    wl[nn] = wn;
    Vsh[row * 192 + c] = a; Vsh[row * 192 + 64 + c] = b; Vsh[row * 192 + 128 + c] = t;
  }
  __syncthreads();
  float Bc = bc[c];
  float acc[4];
  for (int nn = 0; nn < 4; ++nn) acc[nn] = wl[nn] * Bc;
  for (int k = 0; k < 64; k += 4) {
    float wc1[4], wc2[4], wv3[4];
    for (int q = 0; q < 4; ++q) {
      wc1[q] = WcT[(k + q) * 64 + c];
      wc2[q] = WcT[(64 + k + q) * 64 + c];
      wv3[q] = WvlrT[(k + q) * 64 + c];
    }
    for (int nn = 0; nn < 4; ++nn) {
      int row = wv * 4 + nn;
      float4 x = *(const float4*)&Vsh[row * 192 + k];
      float4 y = *(const float4*)&Vsh[row * 192 + 64 + k];
      float4 z = *(const float4*)&Vsh[row * 192 + 128 + k];
      acc[nn] += x.x * wc1[0] + x.y * wc1[1] + x.z * wc1[2] + x.w * wc1[3]
               + y.x * wc2[0] + y.y * wc2[1] + y.z * wc2[2] + y.w * wc2[3]
               + z.x * wv3[0] + z.y * wv3[1] + z.z * wv3[2] + z.w * wv3[3];
    }
  }
  for (int nn = 0; nn < 4; ++nn) {
    int m = mb + wv * 4 + nn;
    if (m < M) out_v[(size_t)m * 64 + c] = fast_tanh(acc[nn]) + vector[(size_t)m * 64 + c];
  }
}

extern "C" void kernel_launch(void* const* d_in, const int* in_sizes, int n_in,
                              void* d_out, int out_size, void* d_ws, size_t ws_size,
                              hipStream_t stream) {
  const float* scalar   = (const float*)d_in[0];
  const float* vector   = (const float*)d_in[1];
  const float* position = (const float*)d_in[2];
  const int*   eidx     = (const int*)d_in[3];
  const float* attr     = (const float*)d_in[4];
  const float* Wss = (const float*)d_in[5];
  const float* bss = (const float*)d_in[6];
  const float* Wvs = (const float*)d_in[7];
  const float* bvs = (const float*)d_in[8];
  const float* Wsl = (const float*)d_in[9];
  const float* bsl = (const float*)d_in[10];
  const float* Wsv = (const float*)d_in[11];
  const float* bsv = (const float*)d_in[12];
  const float* Wvv = (const float*)d_in[13];
  const float* bvv = (const float*)d_in[14];
  const float* Wvl = (const float*)d_in[15];
  const float* bvl = (const float*)d_in[16];

  int N = in_sizes[0] / 64;
  int E = in_sizes[4];
  int M = 3 * N;

  char* wsb = (char*)d_ws;
  size_t off = 0;
  auto alloc = [&](size_t bytes) -> char* {
    char* p = wsb + off;
    off += (bytes + 255) & ~(size_t)255;
    return p;
  };
  float*  deg    = (float*)alloc((size_t)N * 4);
  int*    cnt    = (int*)alloc((size_t)N * 4);
  float*  dis    = (float*)alloc((size_t)N * 4);
  int*    rowptr = (int*)alloc((size_t)(N + 1) * 4);
  int*    cursor = (int*)alloc((size_t)N * 4);
  float4* erecA  = (float4*)alloc((size_t)E * 16);
  float*  erecB  = (float*)alloc((size_t)E * 4);
  u16*    rec_i  = (u16*)alloc((size_t)N * 320 * 2);
  u16*    rec_j  = (u16*)alloc((size_t)N * 512 * 2);
  float*  U      = (float*)alloc((size_t)N * 128 * 4);
  float*  tac    = (float*)alloc((size_t)N * 192 * 4);
  float*  gac    = (float*)alloc((size_t)N * 192 * 4);
  float*  wsum   = (float*)alloc((size_t)N * 4);
  float*  WT_sc  = (float*)alloc(64 * 256 * 4);
  float*  WT_v   = (float*)alloc(64 * 128 * 4);
  float*  WslT   = (float*)alloc(128 * 64 * 4);
  float*  WcT    = (float*)alloc(128 * 64 * 4);
  float*  WvlrT  = (float*)alloc(64 * 64 * 4);
  float*  bc     = (float*)alloc(64 * 4);
  int*    flag   = (int*)alloc(4);
  (void)ws_size; (void)n_in; (void)out_size;

  // zero deg + cnt (contiguous)
  hipMemsetAsync(deg, 0, (size_t)((char*)dis - (char*)deg), stream);

  k_detect<<<1, 256, 0, stream>>>(eidx, flag, E);
  k_prep_weights<<<1, 256, 0, stream>>>(Wss, Wvs, Wsl, Wsv, Wvv, Wvl, bvv, bvl,
                                        WT_sc, WT_v, WslT, WcT, WvlrT, bc);
  k_deg<<<(E + 255) / 256, 256, 0, stream>>>(eidx, flag, attr, deg, cnt, E);
  k_dis<<<(N + 255) / 256, 256, 0, stream>>>(deg, dis, N);
  k_scan<<<1, 1024, 0, stream>>>(cnt, rowptr, cursor, N, E);
  k_fill<<<(E + 255) / 256, 256, 0, stream>>>(eidx, flag, attr, dis, position, cursor, erecA, erecB, E);
  k_gemm_sc<<<(N + 63) / 64, 256, 0, stream>>>(scalar, WT_sc, rec_i, rec_j, N);
  k_gemm_v<<<(M + 63) / 64, 256, 0, stream>>>(vector, WT_v, rec_i, rec_j, M);
  k_edges<<<(N + 3) / 4, 256, 0, stream>>>(rec_i, rec_j, erecA, erecB, rowptr, position,
                                           bss, bvs, bsv, U, tac, gac, wsum, N);
  k_final_s<<<(N + 15) / 16, 256, 0, stream>>>(U, wsum, WslT, bsl, scalar, (float*)d_out, N);
  k_final_v<<<(M + 15) / 16, 256, 0, stream>>>(tac, gac, wsum, vector, WcT, WvlrT, bc,
                                               (float*)d_out + (size_t)N * 64, M);
}

// Round 2
// 1092.524 us; speedup vs baseline: 1.7372x; 1.7372x over previous
//
#include <hip/hip_runtime.h>
#include <cstdint>
#include <cstddef>

typedef unsigned int   u32;
typedef unsigned short u16;

__device__ __forceinline__ float bf2f(u32 bits16) { return __uint_as_float(bits16 << 16); }
__device__ __forceinline__ u16 f2bf(float f) {
  u32 u = __float_as_uint(f);
  u = u + 0x7FFFu + ((u >> 16) & 1u);   // round-to-nearest-even
  return (u16)(u >> 16);
}
__device__ __forceinline__ float lo16(u32 w) { return bf2f(w & 0xFFFFu); }
__device__ __forceinline__ float hi16(u32 w) { return bf2f(w >> 16); }
__device__ __forceinline__ float fast_silu(float x) { return __fdividef(x, 1.0f + __expf(-x)); }
__device__ __forceinline__ float fast_tanh(float z) { return 1.0f - __fdividef(2.0f, 1.0f + __expf(2.0f * z)); }

// ---- edge_index may be int32 or int64 in device memory; detect at runtime ----
__global__ void k_detect(const int* eidx, int* flag, int E) {
  __shared__ int zc;
  if (threadIdx.x == 0) zc = 0;
  __syncthreads();
  int n = (E < 1024) ? E : 1024;
  int local = 0;
  for (int i = threadIdx.x; i < n; i += 256) {
    if (eidx[2 * i + 1] == 0) local++;   // high words if int64 (all 0), else row values (rarely 0)
  }
  atomicAdd(&zc, local);
  __syncthreads();
  if (threadIdx.x == 0) *flag = (zc >= (n >> 1)) ? 1 : 0;
}

__device__ __forceinline__ int load_idx(const int* eidx, int is64, long long pos) {
  if (is64) return (int)(((const long long*)eidx)[pos]);
  return eidx[pos];
}

// ---- weight prep ----
// WT_sc[k*256+j]: j<64 a_i (Wss left), <128 a_j (Wss right), <192 c_i (Wsv left), <256 c_j (Wsv right)
// WT_v[k*128+j]:  j<64 b_i (Wvs left), <128 b_j (Wvs right)
// Wsl2[k2*64+c]:  packed bf16 pair (Wsl[c][2k2], Wsl[c][2k2+1])
// Wv6[(m*32+k2)*64+c]: m=0 Wc1=Wc[c][2k2..], m=1 Wc2=Wc[c][64+2k2..], m=2 Wvlr=Wvl[c][64+2k2..]
//   where Wc = Wvl_left @ Wvv;  bc = Wvl_left @ bvv + bvl
__global__ void k_prep_weights(const float* Wss, const float* Wvs, const float* Wsl,
                               const float* Wsv, const float* Wvv, const float* Wvl,
                               const float* bvv, const float* bvl,
                               float* WT_sc, float* WT_v, u32* Wsl2, u32* Wv6,
                               float* WcTmp, float* bc) {
  int tid = threadIdx.x;
  for (int o = tid; o < 64 * 256; o += 256) {
    int k = o >> 8, j = o & 255;
    float v;
    if (j < 64)       v = Wss[j * 128 + k];
    else if (j < 128) v = Wss[(j - 64) * 128 + 64 + k];
    else if (j < 192) v = Wsv[(j - 128) * 128 + k];
    else              v = Wsv[(j - 192) * 128 + 64 + k];
    WT_sc[o] = v;
  }
  for (int o = tid; o < 64 * 128; o += 256) {
    int k = o >> 7, j = o & 127;
    WT_v[o] = (j < 64) ? Wvs[j * 128 + k] : Wvs[(j - 64) * 128 + 64 + k];
  }
  for (int o = tid; o < 64 * 128; o += 256) {  // WcTmp[c*128+kk] = (Wvl_l @ Wvv)[c][kk]
    int c = o >> 7, kk = o & 127;
    float s = 0.f;
    for (int m = 0; m < 64; ++m) s += Wvl[c * 128 + m] * Wvv[m * 128 + kk];
    WcTmp[o] = s;
  }
  if (tid < 64) {
    float s = 0.f;
    for (int m = 0; m < 64; ++m) s += Wvl[tid * 128 + m] * bvv[m];
    bc[tid] = s + bvl[tid];
  }
  __syncthreads();
  for (int o = tid; o < 64 * 64; o += 256) {
    int k2 = o >> 6, c = o & 63;
    Wsl2[o] = (u32)f2bf(Wsl[c * 128 + 2 * k2]) | ((u32)f2bf(Wsl[c * 128 + 2 * k2 + 1]) << 16);
  }
  for (int o = tid; o < 3 * 32 * 64; o += 256) {
    int m = o >> 11, rem = o & 2047, k2 = rem >> 6, c = rem & 63;
    float w0, w1;
    if (m == 0)      { w0 = WcTmp[c * 128 + 2 * k2];       w1 = WcTmp[c * 128 + 2 * k2 + 1]; }
    else if (m == 1) { w0 = WcTmp[c * 128 + 64 + 2 * k2];  w1 = WcTmp[c * 128 + 64 + 2 * k2 + 1]; }
    else             { w0 = Wvl[c * 128 + 64 + 2 * k2];    w1 = Wvl[c * 128 + 64 + 2 * k2 + 1]; }
    Wv6[o] = (u32)f2bf(w0) | ((u32)f2bf(w1) << 16);
  }
}

__global__ void k_deg(const int* eidx, const int* flag, const float* attr,
                      float* deg, int* cnt, int E) {
  int e = blockIdx.x * 256 + threadIdx.x;
  if (e >= E) return;
  int is64 = *flag;
  int col = load_idx(eidx, is64, (long long)E + e);
  atomicAdd(&deg[col], attr[e]);
  atomicAdd(&cnt[col], 1);
}

__global__ void k_dis(const float* deg, float* dis, int N) {
  int i = blockIdx.x * 256 + threadIdx.x;
  if (i < N) { float d = deg[i]; dis[i] = (d > 0.f) ? rsqrtf(d) : 0.f; }
}

__global__ void k_scan(const int* cnt, int* rowptr, int* cursor, int N, int E) {
  __shared__ int lds[1024];
  int tid = threadIdx.x;
  int CH = (N + 1023) / 1024;
  int base = tid * CH;
  int s = 0;
  for (int j = 0; j < CH; ++j) { int idx = base + j; if (idx < N) s += cnt[idx]; }
  lds[tid] = s;
  __syncthreads();
  for (int off = 1; off < 1024; off <<= 1) {
    int v = (tid >= off) ? lds[tid - off] : 0;
    __syncthreads();
    lds[tid] += v;
    __syncthreads();
  }
  int pre = (tid == 0) ? 0 : lds[tid - 1];
  for (int j = 0; j < CH; ++j) {
    int idx = base + j;
    if (idx < N) { rowptr[idx] = pre; cursor[idx] = pre; pre += cnt[idx]; }
  }
  if (tid == 0) rowptr[N] = E;
}

// CSR fill: erecA[p]={norm, row, pos_j.x, pos_j.y}, erecB[p]=pos_j.z
__global__ void k_fill(const int* eidx, const int* flag, const float* attr, const float* dis,
                       const float* pos, int* cursor, float4* erecA, float* erecB, int E) {
  int e = blockIdx.x * 256 + threadIdx.x;
  if (e >= E) return;
  int is64 = *flag;
  int r  = load_idx(eidx, is64, e);
  int cl = load_idx(eidx, is64, (long long)E + e);
  float nrm = dis[r] * dis[cl] * attr[e];
  int p = atomicAdd(&cursor[cl], 1);
  erecA[p] = make_float4(nrm, __int_as_float(r), pos[r * 3 + 0], pos[r * 3 + 1]);
  erecB[p] = pos[r * 3 + 2];
}

// node GEMM: [N,64] @ WT[64,256] -> bf16 records.
// rec_i[n]: 512 u16, lane granule c*8: {a_i, c_i, b_i0, b_i1, b_i2, pad, pad, pad}
// rec_j[n]: 512 u16, lane granule c*8: {a_j, c_j, b_j0, b_j1, b_j2, v_j0, v_j1, v_j2}
__global__ void k_gemm_sc(const float* X, const float* WT, u16* rec_i, u16* rec_j, int N) {
  __shared__ float Xs[64 * 68];
  __shared__ float Ws[64 * 68];
  int tid = threadIdx.x;
  int nb = blockIdx.x * 64;
  for (int i = 0; i < 16; ++i) {
    int flat = tid + i * 256;
    int r = flat >> 6, k = flat & 63;
    Xs[k * 68 + r] = (nb + r < N) ? X[(size_t)(nb + r) * 64 + k] : 0.f;
  }
  int ty = tid >> 4, tx = tid & 15;
  int r0 = ty * 4, c0 = tx * 4;
  for (int jt = 0; jt < 4; ++jt) {
    __syncthreads();
    for (int i = 0; i < 16; ++i) {
      int flat = tid + i * 256;
      int k = flat >> 6, c = flat & 63;
      Ws[k * 68 + c] = WT[k * 256 + jt * 64 + c];
    }
    __syncthreads();
    float acc[4][4] = {};
    for (int k = 0; k < 64; ++k) {
      float4 a = *(const float4*)&Xs[k * 68 + r0];
      float4 b = *(const float4*)&Ws[k * 68 + c0];
      acc[0][0] += a.x * b.x; acc[0][1] += a.x * b.y; acc[0][2] += a.x * b.z; acc[0][3] += a.x * b.w;
      acc[1][0] += a.y * b.x; acc[1][1] += a.y * b.y; acc[1][2] += a.y * b.z; acc[1][3] += a.y * b.w;
      acc[2][0] += a.z * b.x; acc[2][1] += a.z * b.y; acc[2][2] += a.z * b.z; acc[2][3] += a.z * b.w;
      acc[3][0] += a.w * b.x; acc[3][1] += a.w * b.y; acc[3][2] += a.w * b.z; acc[3][3] += a.w * b.w;
    }
    for (int ii = 0; ii < 4; ++ii) {
      int n = nb + r0 + ii;
      if (n >= N) continue;
      for (int jj = 0; jj < 4; ++jj) {
        int cc = c0 + jj;
        u16 h = f2bf(acc[ii][jj]);
        if (jt == 0)      rec_i[(size_t)n * 512 + cc * 8 + 0] = h;
        else if (jt == 1) rec_j[(size_t)n * 512 + cc * 8 + 0] = h;
        else if (jt == 2) rec_i[(size_t)n * 512 + cc * 8 + 1] = h;
        else              rec_j[(size_t)n * 512 + cc * 8 + 1] = h;
      }
    }
  }
}

// vector GEMM: [3N,64] @ WT[64,128] -> b_i/b_j slots; also bf16 copy of vector -> v_j slots
__global__ void k_gemm_v(const float* X, const float* WT, u16* rec_i, u16* rec_j, int M) {
  __shared__ float Xs[64 * 68];
  __shared__ float Ws[64 * 68];
  int tid = threadIdx.x;
  int mb = blockIdx.x * 64;
  for (int i = 0; i < 16; ++i) {
    int flat = tid + i * 256;
    int r = flat >> 6, k = flat & 63;
    Xs[k * 68 + r] = (mb + r < M) ? X[(size_t)(mb + r) * 64 + k] : 0.f;
  }
  __syncthreads();
  for (int i = 0; i < 16; ++i) {   // bf16 copy of vector into rec_j slots 5..7
    int flat = tid + i * 256;
    int r = flat >> 6, k = flat & 63;
    int m = mb + r;
    if (m < M) {
      int n = m / 3, d = m - n * 3;
      rec_j[(size_t)n * 512 + k * 8 + 5 + d] = f2bf(Xs[k * 68 + r]);
    }
  }
  int ty = tid >> 4, tx = tid & 15;
  int r0 = ty * 4, c0 = tx * 4;
  for (int jt = 0; jt < 2; ++jt) {
    __syncthreads();
    for (int i = 0; i < 16; ++i) {
      int flat = tid + i * 256;
      int k = flat >> 6, c = flat & 63;
      Ws[k * 68 + c] = WT[k * 128 + jt * 64 + c];
    }
    __syncthreads();
    float acc[4][4] = {};
    for (int k = 0; k < 64; ++k) {
      float4 a = *(const float4*)&Xs[k * 68 + r0];
      float4 b = *(const float4*)&Ws[k * 68 + c0];
      acc[0][0] += a.x * b.x; acc[0][1] += a.x * b.y; acc[0][2] += a.x * b.z; acc[0][3] += a.x * b.w;
      acc[1][0] += a.y * b.x; acc[1][1] += a.y * b.y; acc[1][2] += a.y * b.z; acc[1][3] += a.y * b.w;
      acc[2][0] += a.z * b.x; acc[2][1] += a.z * b.y; acc[2][2] += a.z * b.z; acc[2][3] += a.z * b.w;
      acc[3][0] += a.w * b.x; acc[3][1] += a.w * b.y; acc[3][2] += a.w * b.z; acc[3][3] += a.w * b.w;
    }
    for (int ii = 0; ii < 4; ++ii) {
      int m = mb + r0 + ii;
      if (m >= M) continue;
      int n = m / 3, d = m - n * 3;
      for (int jj = 0; jj < 4; ++jj) {
        int cc = c0 + jj;
        u16 h = f2bf(acc[ii][jj]);
        if (jt == 0) rec_i[(size_t)n * 512 + cc * 8 + 2 + d] = h;
        else         rec_j[(size_t)n * 512 + cc * 8 + 2 + d] = h;
      }
    }
  }
}

// Fused hot kernel: one wave per node, CSR gather loop with depth-2 prefetch,
// then in-wave epilogue matvecs using bf16 weight tables staged in LDS.
__global__ __launch_bounds__(512) void k_edges(
    const u16* __restrict__ rec_i, const u16* __restrict__ rec_j,
    const float4* __restrict__ erecA, const float* __restrict__ erecB,
    const int* __restrict__ rowptr, const float* __restrict__ pos,
    const float* __restrict__ scalar, const float* __restrict__ vector,
    const float* __restrict__ bss, const float* __restrict__ bvs,
    const float* __restrict__ bsv, const float* __restrict__ bsl,
    const u32* __restrict__ Wsl2g, const u32* __restrict__ Wv6g,
    const float* __restrict__ bcg,
    float* __restrict__ out_s, float* __restrict__ out_v, int N) {
  __shared__ u32 Wsl2[64 * 64];      // 16 KB
  __shared__ u32 Wv6[3 * 32 * 64];   // 24 KB
  __shared__ float smst[8 * 192];    // 6 KB, wave-private 192-float stage each
  int tid = threadIdx.x, lane = tid & 63, wv = tid >> 6;
  for (int o = tid; o < 4096; o += 512) Wsl2[o] = Wsl2g[o];
  for (int o = tid; o < 6144; o += 512) Wv6[o] = Wv6g[o];

  int node = blockIdx.x * 8 + wv;
  if (node >= N) node = N - 1;   // duplicate work; same values written (grid is exact anyway)

  uint4 riv = *(const uint4*)(rec_i + (size_t)node * 512 + lane * 8);
  float a_i = lo16(riv.x), c_i = hi16(riv.x);
  float bi0 = lo16(riv.y), bi1 = hi16(riv.y), bi2 = lo16(riv.z);
  float pix = pos[node * 3 + 0], piy = pos[node * 3 + 1], piz = pos[node * 3 + 2];
  float Bss = bss[lane], Bvs = bvs[lane], Bsv = bsv[lane];
  float bsl_c = bsl[lane], bc_c = bcg[lane];

  float us = 0, uv = 0, t0 = 0, t1 = 0, t2 = 0, g0 = 0, g1 = 0, g2 = 0, wa = 0;
  int rp = rowptr[node], re = rowptr[node + 1];
  for (int base = rp; base < re; base += 64) {
    int m = min(64, re - base);
    float4 eA = make_float4(0.f, 0.f, 0.f, 0.f);
    float  eB = 0.f;
    if (lane < m) { eA = erecA[base + lane]; eB = erecB[base + lane]; }
    uint4 rv0 = make_uint4(0, 0, 0, 0), rv1 = make_uint4(0, 0, 0, 0);
    {
      int r0i = __float_as_int(__shfl(eA.y, 0));
      rv0 = *(const uint4*)(rec_j + (size_t)r0i * 512 + lane * 8);
    }
    if (m > 1) {
      int r1i = __float_as_int(__shfl(eA.y, 1));
      rv1 = *(const uint4*)(rec_j + (size_t)r1i * 512 + lane * 8);
    }
    for (int j = 0; j < m; ++j) {
      uint4 cur = rv0;
      rv0 = rv1;
      if (j + 2 < m) {
        int rn = __float_as_int(__shfl(eA.y, j + 2));
        rv1 = *(const uint4*)(rec_j + (size_t)rn * 512 + lane * 8);
      }
      float nrm = __shfl(eA.x, j);
      float pjx = __shfl(eA.z, j), pjy = __shfl(eA.w, j), pjz = __shfl(eB, j);
      float aj  = lo16(cur.x), cj  = hi16(cur.x);
      float bj0 = lo16(cur.y), bj1 = hi16(cur.y), bj2 = lo16(cur.z);
      float vj0 = hi16(cur.z), vj1 = lo16(cur.w), vj2 = hi16(cur.w);
      float px = pix - pjx, py = piy - pjy, pz = piz - pjz;
      float s2s = fast_silu(a_i + aj + Bss);
      float y   = (bi0 + bj0 + Bvs) * px + (bi1 + bj1 + Bvs) * py + (bi2 + bj2 + Bvs) * pz;
      float v2s = fast_silu(y);
      float sp  = c_i + cj + Bsv;
      us += nrm * s2s; uv += nrm * v2s;
      t0 += nrm * fast_tanh(sp * px);
      t1 += nrm * fast_tanh(sp * py);
      t2 += nrm * fast_tanh(sp * pz);
      g0 += nrm * vj0; g1 += nrm * vj1; g2 += nrm * vj2;
      wa += nrm;
    }
  }

  // ---- epilogue: scalar head ----
  float* mys = &smst[wv * 192];
  mys[lane] = us; mys[64 + lane] = uv;
  __syncthreads();   // also covers the weight-table staging at kernel start
  float acc = wa * bsl_c;
  #pragma unroll 8
  for (int k2 = 0; k2 < 64; ++k2) {
    u32 w = Wsl2[k2 * 64 + lane];
    acc += mys[2 * k2] * lo16(w) + mys[2 * k2 + 1] * hi16(w);
  }
  out_s[(size_t)node * 64 + lane] = fast_silu(acc) + scalar[(size_t)node * 64 + lane];

  // ---- epilogue: vector head, one spatial dim at a time ----
  float gg[3] = {g0, g1, g2}, tt[3] = {t0, t1, t2};
  #pragma unroll
  for (int d = 0; d < 3; ++d) {
    __syncthreads();
    float vid = vector[((size_t)node * 3 + d) * 64 + lane];
    mys[lane] = wa * vid; mys[64 + lane] = gg[d]; mys[128 + lane] = tt[d];
    __syncthreads();
    float a2 = wa * bc_c;
    #pragma unroll 8
    for (int k2 = 0; k2 < 32; ++k2) {
      u32 w0 = Wv6[k2 * 64 + lane];
      u32 w1 = Wv6[(32 + k2) * 64 + lane];
      u32 w2 = Wv6[(64 + k2) * 64 + lane];
      a2 += mys[2 * k2]       * lo16(w0) + mys[2 * k2 + 1]       * hi16(w0)
          + mys[64 + 2 * k2]  * lo16(w1) + mys[64 + 2 * k2 + 1]  * hi16(w1)
          + mys[128 + 2 * k2] * lo16(w2) + mys[128 + 2 * k2 + 1] * hi16(w2);
    }
    out_v[((size_t)node * 3 + d) * 64 + lane] = fast_tanh(a2) + vid;
  }
}

extern "C" void kernel_launch(void* const* d_in, const int* in_sizes, int n_in,
                              void* d_out, int out_size, void* d_ws, size_t ws_size,
                              hipStream_t stream) {
  const float* scalar   = (const float*)d_in[0];
  const float* vector   = (const float*)d_in[1];
  const float* position = (const float*)d_in[2];
  const int*   eidx     = (const int*)d_in[3];
  const float* attr     = (const float*)d_in[4];
  const float* Wss = (const float*)d_in[5];
  const float* bss = (const float*)d_in[6];
  const float* Wvs = (const float*)d_in[7];
  const float* bvs = (const float*)d_in[8];
  const float* Wsl = (const float*)d_in[9];
  const float* bsl = (const float*)d_in[10];
  const float* Wsv = (const float*)d_in[11];
  const float* bsv = (const float*)d_in[12];
  const float* Wvv = (const float*)d_in[13];
  const float* bvv = (const float*)d_in[14];
  const float* Wvl = (const float*)d_in[15];
  const float* bvl = (const float*)d_in[16];

  int N = in_sizes[0] / 64;
  int E = in_sizes[4];
  int M = 3 * N;

  char* wsb = (char*)d_ws;
  size_t off = 0;
  auto alloc = [&](size_t bytes) -> char* {
    char* p = wsb + off;
    off += (bytes + 255) & ~(size_t)255;
    return p;
  };
  float*  deg    = (float*)alloc((size_t)N * 4);
  int*    cnt    = (int*)alloc((size_t)N * 4);
  float*  dis    = (float*)alloc((size_t)N * 4);
  int*    rowptr = (int*)alloc((size_t)(N + 1) * 4);
  int*    cursor = (int*)alloc((size_t)N * 4);
  float4* erecA  = (float4*)alloc((size_t)E * 16);
  float*  erecB  = (float*)alloc((size_t)E * 4);
  u16*    rec_i  = (u16*)alloc((size_t)N * 512 * 2);
  u16*    rec_j  = (u16*)alloc((size_t)N * 512 * 2);
  float*  WT_sc  = (float*)alloc(64 * 256 * 4);
  float*  WT_v   = (float*)alloc(64 * 128 * 4);
  u32*    Wsl2   = (u32*)alloc(64 * 64 * 4);
  u32*    Wv6    = (u32*)alloc(3 * 32 * 64 * 4);
  float*  WcTmp  = (float*)alloc(64 * 128 * 4);
  float*  bc     = (float*)alloc(64 * 4);
  int*    flag   = (int*)alloc(4);
  (void)ws_size; (void)n_in; (void)out_size;

  // zero deg + cnt (contiguous region)
  hipMemsetAsync(deg, 0, (size_t)((char*)dis - (char*)deg), stream);

  k_detect<<<1, 256, 0, stream>>>(eidx, flag, E);
  k_prep_weights<<<1, 256, 0, stream>>>(Wss, Wvs, Wsl, Wsv, Wvv, Wvl, bvv, bvl,
                                        WT_sc, WT_v, Wsl2, Wv6, WcTmp, bc);
  k_deg<<<(E + 255) / 256, 256, 0, stream>>>(eidx, flag, attr, deg, cnt, E);
  k_dis<<<(N + 255) / 256, 256, 0, stream>>>(deg, dis, N);
  k_scan<<<1, 1024, 0, stream>>>(cnt, rowptr, cursor, N, E);
  k_fill<<<(E + 255) / 256, 256, 0, stream>>>(eidx, flag, attr, dis, position, cursor, erecA, erecB, E);
  k_gemm_sc<<<(N + 63) / 64, 256, 0, stream>>>(scalar, WT_sc, rec_i, rec_j, N);
  k_gemm_v<<<(M + 63) / 64, 256, 0, stream>>>(vector, WT_v, rec_i, rec_j, M);
  k_edges<<<(N + 7) / 8, 512, 0, stream>>>(rec_i, rec_j, erecA, erecB, rowptr, position,
                                           scalar, vector, bss, bvs, bsv, bsl,
                                           Wsl2, Wv6, bc,
                                           (float*)d_out, (float*)d_out + (size_t)N * 64, N);
}

// Round 3
// 898.309 us; speedup vs baseline: 2.1128x; 1.2162x over previous
//
#include <hip/hip_runtime.h>
#include <cstdint>
#include <cstddef>

typedef unsigned int   u32;
typedef unsigned short u16;

__device__ __forceinline__ float bf2f(u32 bits16) { return __uint_as_float(bits16 << 16); }
__device__ __forceinline__ u16 f2bf(float f) {
  u32 u = __float_as_uint(f);
  u = u + 0x7FFFu + ((u >> 16) & 1u);   // round-to-nearest-even
  return (u16)(u >> 16);
}
__device__ __forceinline__ u32 pk(float a, float b) {
  return (u32)f2bf(a) | ((u32)f2bf(b) << 16);
}
__device__ __forceinline__ float lo16(u32 w) { return bf2f(w & 0xFFFFu); }
__device__ __forceinline__ float hi16(u32 w) { return bf2f(w >> 16); }
__device__ __forceinline__ float frcp(float x) { return __builtin_amdgcn_rcpf(x); }
__device__ __forceinline__ float rlanef(float v, int l) {
  return __int_as_float(__builtin_amdgcn_readlane(__float_as_int(v), l));
}

// ---- edge_index may be int32 or int64 in device memory; detect at runtime ----
__global__ void k_detect(const int* eidx, int* flag, int E) {
  __shared__ int zc;
  if (threadIdx.x == 0) zc = 0;
  __syncthreads();
  int n = (E < 1024) ? E : 1024;
  int local = 0;
  for (int i = threadIdx.x; i < n; i += 256) {
    if (eidx[2 * i + 1] == 0) local++;   // high words if int64 (all 0), else row values (rarely 0)
  }
  atomicAdd(&zc, local);
  __syncthreads();
  if (threadIdx.x == 0) *flag = (zc >= (n >> 1)) ? 1 : 0;
}

__device__ __forceinline__ int load_idx(const int* eidx, int is64, long long pos) {
  if (is64) return (int)(((const long long*)eidx)[pos]);
  return eidx[pos];
}

// ---- weight prep ----
// WT_sc[k*256+j]: j<64 a_i (Wss left), <128 a_j (Wss right), <192 c_i (Wsv left), <256 c_j (Wsv right)
// WT_v[k*128+j]:  j<64 b_i (Wvs left), <128 b_j (Wvs right)
// Wsl2[(g*64+c)*2+h] = pack(Wsl[c][4g+2h], Wsl[c][4g+2h+1]), g<32  (b64-readable pairs)
// Wv6: 3 matrices of 2048 u32 each, same pair layout with g<16:
//   m=0: Wc[c][k] (k<64), m=1: Wc[c][64+k], m=2: Wvl[c][64+k];  Wc = Wvl_left@Wvv
//   bc = Wvl_left@bvv + bvl
__global__ void k_prep_weights(const float* Wss, const float* Wvs, const float* Wsl,
                               const float* Wsv, const float* Wvv, const float* Wvl,
                               const float* bvv, const float* bvl,
                               float* WT_sc, float* WT_v, u32* Wsl2, u32* Wv6,
                               float* WcTmp, float* bc) {
  int tid = threadIdx.x;
  for (int o = tid; o < 64 * 256; o += 256) {
    int k = o >> 8, j = o & 255;
    float v;
    if (j < 64)       v = Wss[j * 128 + k];
    else if (j < 128) v = Wss[(j - 64) * 128 + 64 + k];
    else if (j < 192) v = Wsv[(j - 128) * 128 + k];
    else              v = Wsv[(j - 192) * 128 + 64 + k];
    WT_sc[o] = v;
  }
  for (int o = tid; o < 64 * 128; o += 256) {
    int k = o >> 7, j = o & 127;
    WT_v[o] = (j < 64) ? Wvs[j * 128 + k] : Wvs[(j - 64) * 128 + 64 + k];
  }
  for (int o = tid; o < 64 * 128; o += 256) {  // WcTmp[c*128+kk] = (Wvl_l @ Wvv)[c][kk]
    int c = o >> 7, kk = o & 127;
    float s = 0.f;
    for (int m = 0; m < 64; ++m) s += Wvl[c * 128 + m] * Wvv[m * 128 + kk];
    WcTmp[o] = s;
  }
  if (tid < 64) {
    float s = 0.f;
    for (int m = 0; m < 64; ++m) s += Wvl[tid * 128 + m] * bvv[m];
    bc[tid] = s + bvl[tid];
  }
  __syncthreads();
  for (int o = tid; o < 4096; o += 256) {
    int h = o & 1, c = (o >> 1) & 63, g = o >> 7;
    int k = 4 * g + 2 * h;
    Wsl2[o] = pk(Wsl[c * 128 + k], Wsl[c * 128 + k + 1]);
  }
  for (int o = tid; o < 6144; o += 256) {
    int mm = o >> 11, rem = o & 2047;
    int h = rem & 1, c = (rem >> 1) & 63, g = rem >> 7;
    int k = 4 * g + 2 * h;
    float w0, w1;
    if (mm == 0)      { w0 = WcTmp[c * 128 + k];       w1 = WcTmp[c * 128 + k + 1]; }
    else if (mm == 1) { w0 = WcTmp[c * 128 + 64 + k];  w1 = WcTmp[c * 128 + 64 + k + 1]; }
    else              { w0 = Wvl[c * 128 + 64 + k];    w1 = Wvl[c * 128 + 64 + k + 1]; }
    Wv6[o] = pk(w0, w1);
  }
}

__global__ void k_deg(const int* eidx, const int* flag, const float* attr,
                      float* deg, int* cnt, int E) {
  int e = blockIdx.x * 256 + threadIdx.x;
  if (e >= E) return;
  int is64 = *flag;
  int col = load_idx(eidx, is64, (long long)E + e);
  atomicAdd(&deg[col], attr[e]);
  atomicAdd(&cnt[col], 1);
}

__global__ void k_dis(const float* deg, float* dis, int N) {
  int i = blockIdx.x * 256 + threadIdx.x;
  if (i < N) { float d = deg[i]; dis[i] = (d > 0.f) ? rsqrtf(d) : 0.f; }
}

__global__ void k_scan(const int* cnt, int* rowptr, int* cursor, int N, int E) {
  __shared__ int lds[1024];
  int tid = threadIdx.x;
  int CH = (N + 1023) / 1024;
  int base = tid * CH;
  int s = 0;
  for (int j = 0; j < CH; ++j) { int idx = base + j; if (idx < N) s += cnt[idx]; }
  lds[tid] = s;
  __syncthreads();
  for (int off = 1; off < 1024; off <<= 1) {
    int v = (tid >= off) ? lds[tid - off] : 0;
    __syncthreads();
    lds[tid] += v;
    __syncthreads();
  }
  int pre = (tid == 0) ? 0 : lds[tid - 1];
  for (int j = 0; j < CH; ++j) {
    int idx = base + j;
    if (idx < N) { rowptr[idx] = pre; cursor[idx] = pre; pre += cnt[idx]; }
  }
  if (tid == 0) rowptr[N] = E;
}

// CSR fill: erecA[p]={norm, dx, dy, dz} (d = pos_i - pos_j), erecI[p]=row
__global__ void k_fill(const int* eidx, const int* flag, const float* attr, const float* dis,
                       const float* pos, int* cursor, float4* erecA, int* erecI, int E) {
  int e = blockIdx.x * 256 + threadIdx.x;
  if (e >= E) return;
  int is64 = *flag;
  int r  = load_idx(eidx, is64, e);
  int cl = load_idx(eidx, is64, (long long)E + e);
  float nrm = dis[r] * dis[cl] * attr[e];
  float dx = pos[cl * 3 + 0] - pos[r * 3 + 0];
  float dy = pos[cl * 3 + 1] - pos[r * 3 + 1];
  float dz = pos[cl * 3 + 2] - pos[r * 3 + 2];
  int p = atomicAdd(&cursor[cl], 1);
  erecA[p] = make_float4(nrm, dx, dy, dz);
  erecI[p] = r;
}

// node GEMM: [N,64] @ WT[64,256] -> bf16 records.
// rec_i[n]: 512 u16, lane granule c*8: {a_i, c_i, b_i0, b_i1, b_i2, pad, pad, pad}
// rec_j[n]: 512 u16, lane granule c*8: {a_j, c_j, b_j0, b_j1, b_j2, v_j0, v_j1, v_j2}
__global__ void k_gemm_sc(const float* X, const float* WT, u16* rec_i, u16* rec_j, int N) {
  __shared__ float Xs[64 * 68];
  __shared__ float Ws[64 * 68];
  int tid = threadIdx.x;
  int nb = blockIdx.x * 64;
  for (int i = 0; i < 16; ++i) {
    int flat = tid + i * 256;
    int r = flat >> 6, k = flat & 63;
    Xs[k * 68 + r] = (nb + r < N) ? X[(size_t)(nb + r) * 64 + k] : 0.f;
  }
  int ty = tid >> 4, tx = tid & 15;
  int r0 = ty * 4, c0 = tx * 4;
  for (int jt = 0; jt < 4; ++jt) {
    __syncthreads();
    for (int i = 0; i < 16; ++i) {
      int flat = tid + i * 256;
      int k = flat >> 6, c = flat & 63;
      Ws[k * 68 + c] = WT[k * 256 + jt * 64 + c];
    }
    __syncthreads();
    float acc[4][4] = {};
    for (int k = 0; k < 64; ++k) {
      float4 a = *(const float4*)&Xs[k * 68 + r0];
      float4 b = *(const float4*)&Ws[k * 68 + c0];
      acc[0][0] += a.x * b.x; acc[0][1] += a.x * b.y; acc[0][2] += a.x * b.z; acc[0][3] += a.x * b.w;
      acc[1][0] += a.y * b.x; acc[1][1] += a.y * b.y; acc[1][2] += a.y * b.z; acc[1][3] += a.y * b.w;
      acc[2][0] += a.z * b.x; acc[2][1] += a.z * b.y; acc[2][2] += a.z * b.z; acc[2][3] += a.z * b.w;
      acc[3][0] += a.w * b.x; acc[3][1] += a.w * b.y; acc[3][2] += a.w * b.z; acc[3][3] += a.w * b.w;
    }
    for (int ii = 0; ii < 4; ++ii) {
      int n = nb + r0 + ii;
      if (n >= N) continue;
      for (int jj = 0; jj < 4; ++jj) {
        int cc = c0 + jj;
        u16 h = f2bf(acc[ii][jj]);
        if (jt == 0)      rec_i[(size_t)n * 512 + cc * 8 + 0] = h;
        else if (jt == 1) rec_j[(size_t)n * 512 + cc * 8 + 0] = h;
        else if (jt == 2) rec_i[(size_t)n * 512 + cc * 8 + 1] = h;
        else              rec_j[(size_t)n * 512 + cc * 8 + 1] = h;
      }
    }
  }
}

// vector GEMM: [3N,64] @ WT[64,128] -> b_i/b_j slots; also bf16 copy of vector -> v_j slots
__global__ void k_gemm_v(const float* X, const float* WT, u16* rec_i, u16* rec_j, int M) {
  __shared__ float Xs[64 * 68];
  __shared__ float Ws[64 * 68];
  int tid = threadIdx.x;
  int mb = blockIdx.x * 64;
  for (int i = 0; i < 16; ++i) {
    int flat = tid + i * 256;
    int r = flat >> 6, k = flat & 63;
    Xs[k * 68 + r] = (mb + r < M) ? X[(size_t)(mb + r) * 64 + k] : 0.f;
  }
  __syncthreads();
  for (int i = 0; i < 16; ++i) {   // bf16 copy of vector into rec_j slots 5..7
    int flat = tid + i * 256;
    int r = flat >> 6, k = flat & 63;
    int m = mb + r;
    if (m < M) {
      int n = m / 3, d = m - n * 3;
      rec_j[(size_t)n * 512 + k * 8 + 5 + d] = f2bf(Xs[k * 68 + r]);
    }
  }
  int ty = tid >> 4, tx = tid & 15;
  int r0 = ty * 4, c0 = tx * 4;
  for (int jt = 0; jt < 2; ++jt) {
    __syncthreads();
    for (int i = 0; i < 16; ++i) {
      int flat = tid + i * 256;
      int k = flat >> 6, c = flat & 63;
      Ws[k * 68 + c] = WT[k * 128 + jt * 64 + c];
    }
    __syncthreads();
    float acc[4][4] = {};
    for (int k = 0; k < 64; ++k) {
      float4 a = *(const float4*)&Xs[k * 68 + r0];
      float4 b = *(const float4*)&Ws[k * 68 + c0];
      acc[0][0] += a.x * b.x; acc[0][1] += a.x * b.y; acc[0][2] += a.x * b.z; acc[0][3] += a.x * b.w;
      acc[1][0] += a.y * b.x; acc[1][1] += a.y * b.y; acc[1][2] += a.y * b.z; acc[1][3] += a.y * b.w;
      acc[2][0] += a.z * b.x; acc[2][1] += a.z * b.y; acc[2][2] += a.z * b.z; acc[2][3] += a.z * b.w;
      acc[3][0] += a.w * b.x; acc[3][1] += a.w * b.y; acc[3][2] += a.w * b.z; acc[3][3] += a.w * b.w;
    }
    for (int ii = 0; ii < 4; ++ii) {
      int m = mb + r0 + ii;
      if (m >= M) continue;
      int n = m / 3, d = m - n * 3;
      for (int jj = 0; jj < 4; ++jj) {
        int cc = c0 + jj;
        u16 h = f2bf(acc[ii][jj]);
        if (jt == 0) rec_i[(size_t)n * 512 + cc * 8 + 2 + d] = h;
        else         rec_j[(size_t)n * 512 + cc * 8 + 2 + d] = h;
      }
    }
  }
}

// Fused hot kernel: one wave per node. Edge broadcasts via v_readlane (no shfl/LDS),
// depth-3 gather prefetch, barrier-free vectorized epilogue.
__global__ __launch_bounds__(512) void k_edges(
    const u16* __restrict__ rec_i, const u16* __restrict__ rec_j,
    const float4* __restrict__ erecA, const int* __restrict__ erecI,
    const int* __restrict__ rowptr,
    const float* __restrict__ scalar, const float* __restrict__ vector,
    const float* __restrict__ bss, const float* __restrict__ bvs,
    const float* __restrict__ bsv, const float* __restrict__ bsl,
    const u32* __restrict__ Wsl2g, const u32* __restrict__ Wv6g,
    const float* __restrict__ bcg,
    float* __restrict__ out_s, float* __restrict__ out_v, int N) {
  __shared__ u32 sWsl[4096];       // 16 KB
  __shared__ u32 sWv[6144];        // 24 KB
  __shared__ float sStage[8 * 192];// 6 KB, wave-private epilogue stage
  int tid = threadIdx.x, lane = tid & 63, wv = tid >> 6;
  for (int o = tid; o < 4096; o += 512) sWsl[o] = Wsl2g[o];
  for (int o = tid; o < 6144; o += 512) sWv[o] = Wv6g[o];
  __syncthreads();   // the only block barrier

  int node = blockIdx.x * 8 + wv;
  if (node >= N) node = N - 1;   // duplicate work, identical writes

  uint4 riv = *(const uint4*)(rec_i + ((size_t)node << 9) + lane * 8);
  float aiB  = lo16(riv.x) + bss[lane];
  float ciB  = hi16(riv.x) + bsv[lane];
  float Bvs  = bvs[lane];
  float bib0 = lo16(riv.y) + Bvs;
  float bib1 = hi16(riv.y) + Bvs;
  float bib2 = lo16(riv.z) + Bvs;
  float bsl_c = bsl[lane], bc_c = bcg[lane];

  float us = 0, uv = 0, t0 = 0, t1 = 0, t2 = 0, g0 = 0, g1 = 0, g2 = 0, wa = 0;
  int rp = rowptr[node], re = rowptr[node + 1];
  for (int base = rp; base < re; base += 64) {
    int m = min(64, re - base);
    float4 eA = make_float4(0.f, 0.f, 0.f, 0.f);
    int eI = 0;
    if (lane < m) { eA = erecA[base + lane]; eI = erecI[base + lane]; }
    uint4 rv0, rv1, rv2;
    {
      int r0 = __builtin_amdgcn_readlane(eI, 0);
      rv0 = *(const uint4*)(rec_j + ((size_t)r0 << 9) + lane * 8);
    }
    rv1 = rv0; rv2 = rv0;
    if (m > 1) {
      int r1 = __builtin_amdgcn_readlane(eI, 1);
      rv1 = *(const uint4*)(rec_j + ((size_t)r1 << 9) + lane * 8);
    }
    if (m > 2) {
      int r2 = __builtin_amdgcn_readlane(eI, 2);
      rv2 = *(const uint4*)(rec_j + ((size_t)r2 << 9) + lane * 8);
    }
    for (int j = 0; j < m; ++j) {
      uint4 cur = rv0; rv0 = rv1; rv1 = rv2;
      if (j + 3 < m) {
        int rn = __builtin_amdgcn_readlane(eI, j + 3);
        rv2 = *(const uint4*)(rec_j + ((size_t)rn << 9) + lane * 8);
      }
      float nrm = rlanef(eA.x, j), dx = rlanef(eA.y, j);
      float dy  = rlanef(eA.z, j), dz = rlanef(eA.w, j);
      float aj  = lo16(cur.x), cj  = hi16(cur.x);
      float bj0 = lo16(cur.y), bj1 = hi16(cur.y), bj2 = lo16(cur.z);
      float vj0 = hi16(cur.z), vj1 = lo16(cur.w), vj2 = hi16(cur.w);
      float xs  = aiB + aj;
      float s2s = xs * frcp(1.f + __expf(-xs));
      float y   = (bib0 + bj0) * dx + (bib1 + bj1) * dy + (bib2 + bj2) * dz;
      float v2s = y * frcp(1.f + __expf(-y));
      float sp2 = 2.f * (ciB + cj);
      float th0 = fmaf(-2.f, frcp(1.f + __expf(sp2 * dx)), 1.f);
      float th1 = fmaf(-2.f, frcp(1.f + __expf(sp2 * dy)), 1.f);
      float th2 = fmaf(-2.f, frcp(1.f + __expf(sp2 * dz)), 1.f);
      us = fmaf(nrm, s2s, us); uv = fmaf(nrm, v2s, uv);
      t0 = fmaf(nrm, th0, t0); t1 = fmaf(nrm, th1, t1); t2 = fmaf(nrm, th2, t2);
      g0 = fmaf(nrm, vj0, g0); g1 = fmaf(nrm, vj1, g1); g2 = fmaf(nrm, vj2, g2);
      wa += nrm;
    }
  }

  // ---- epilogue: scalar head (wave-local, no block barrier) ----
  float* mys = &sStage[wv * 192];
  mys[lane] = us; mys[64 + lane] = uv;
  __threadfence_block();
  float acc = wa * bsl_c;
  #pragma unroll
  for (int g = 0; g < 32; ++g) {
    float4 u = *(const float4*)&mys[4 * g];
    uint2 w = *(const uint2*)&sWsl[(g * 64 + lane) * 2];
    acc = fmaf(u.x, lo16(w.x), acc);
    acc = fmaf(u.y, hi16(w.x), acc);
    acc = fmaf(u.z, lo16(w.y), acc);
    acc = fmaf(u.w, hi16(w.y), acc);
  }
  size_t so = ((size_t)node << 6) + lane;
  out_s[so] = acc * frcp(1.f + __expf(-acc)) + scalar[so];

  // ---- epilogue: vector head ----
  float gg[3] = {g0, g1, g2}, tt[3] = {t0, t1, t2};
  #pragma unroll
  for (int d = 0; d < 3; ++d) {
    size_t vo = (((size_t)node * 3 + d) << 6) + lane;
    float vid = vector[vo];
    __threadfence_block();
    mys[lane] = wa * vid; mys[64 + lane] = gg[d]; mys[128 + lane] = tt[d];
    __threadfence_block();
    float a2 = wa * bc_c;
    #pragma unroll
    for (int g = 0; g < 16; ++g) {
      float4 xu = *(const float4*)&mys[4 * g];
      float4 yu = *(const float4*)&mys[64 + 4 * g];
      float4 zu = *(const float4*)&mys[128 + 4 * g];
      int bi = (g * 64 + lane) * 2;
      uint2 wA = *(const uint2*)&sWv[bi];
      uint2 wB = *(const uint2*)&sWv[2048 + bi];
      uint2 wC = *(const uint2*)&sWv[4096 + bi];
      a2 = fmaf(xu.x, lo16(wA.x), a2); a2 = fmaf(xu.y, hi16(wA.x), a2);
      a2 = fmaf(xu.z, lo16(wA.y), a2); a2 = fmaf(xu.w, hi16(wA.y), a2);
      a2 = fmaf(yu.x, lo16(wB.x), a2); a2 = fmaf(yu.y, hi16(wB.x), a2);
      a2 = fmaf(yu.z, lo16(wB.y), a2); a2 = fmaf(yu.w, hi16(wB.y), a2);
      a2 = fmaf(zu.x, lo16(wC.x), a2); a2 = fmaf(zu.y, hi16(wC.x), a2);
      a2 = fmaf(zu.z, lo16(wC.y), a2); a2 = fmaf(zu.w, hi16(wC.y), a2);
    }
    float th = fmaf(-2.f, frcp(1.f + __expf(2.f * a2)), 1.f);
    out_v[vo] = th + vid;
  }
}

extern "C" void kernel_launch(void* const* d_in, const int* in_sizes, int n_in,
                              void* d_out, int out_size, void* d_ws, size_t ws_size,
                              hipStream_t stream) {
  const float* scalar   = (const float*)d_in[0];
  const float* vector   = (const float*)d_in[1];
  const float* position = (const float*)d_in[2];
  const int*   eidx     = (const int*)d_in[3];
  const float* attr     = (const float*)d_in[4];
  const float* Wss = (const float*)d_in[5];
  const float* bss = (const float*)d_in[6];
  const float* Wvs = (const float*)d_in[7];
  const float* bvs = (const float*)d_in[8];
  const float* Wsl = (const float*)d_in[9];
  const float* bsl = (const float*)d_in[10];
  const float* Wsv = (const float*)d_in[11];
  const float* bsv = (const float*)d_in[12];
  const float* Wvv = (const float*)d_in[13];
  const float* bvv = (const float*)d_in[14];
  const float* Wvl = (const float*)d_in[15];
  const float* bvl = (const float*)d_in[16];

  int N = in_sizes[0] / 64;
  int E = in_sizes[4];
  int M = 3 * N;

  char* wsb = (char*)d_ws;
  size_t off = 0;
  auto alloc = [&](size_t bytes) -> char* {
    char* p = wsb + off;
    off += (bytes + 255) & ~(size_t)255;
    return p;
  };
  float*  deg    = (float*)alloc((size_t)N * 4);
  int*    cnt    = (int*)alloc((size_t)N * 4);
  float*  dis    = (float*)alloc((size_t)N * 4);
  int*    rowptr = (int*)alloc((size_t)(N + 1) * 4);
  int*    cursor = (int*)alloc((size_t)N * 4);
  float4* erecA  = (float4*)alloc((size_t)E * 16);
  int*    erecI  = (int*)alloc((size_t)E * 4);
  u16*    rec_i  = (u16*)alloc((size_t)N * 512 * 2);
  u16*    rec_j  = (u16*)alloc((size_t)N * 512 * 2);
  float*  WT_sc  = (float*)alloc(64 * 256 * 4);
  float*  WT_v   = (float*)alloc(64 * 128 * 4);
  u32*    Wsl2   = (u32*)alloc(4096 * 4);
  u32*    Wv6    = (u32*)alloc(6144 * 4);
  float*  WcTmp  = (float*)alloc(64 * 128 * 4);
  float*  bc     = (float*)alloc(64 * 4);
  int*    flag   = (int*)alloc(4);
  (void)ws_size; (void)n_in; (void)out_size;

  // zero deg + cnt (contiguous region)
  hipMemsetAsync(deg, 0, (size_t)((char*)dis - (char*)deg), stream);

  k_detect<<<1, 256, 0, stream>>>(eidx, flag, E);
  k_prep_weights<<<1, 256, 0, stream>>>(Wss, Wvs, Wsl, Wsv, Wvv, Wvl, bvv, bvl,
                                        WT_sc, WT_v, Wsl2, Wv6, WcTmp, bc);
  k_deg<<<(E + 255) / 256, 256, 0, stream>>>(eidx, flag, attr, deg, cnt, E);
  k_dis<<<(N + 255) / 256, 256, 0, stream>>>(deg, dis, N);
  k_scan<<<1, 1024, 0, stream>>>(cnt, rowptr, cursor, N, E);
  k_fill<<<(E + 255) / 256, 256, 0, stream>>>(eidx, flag, attr, dis, position, cursor, erecA, erecI, E);
  k_gemm_sc<<<(N + 63) / 64, 256, 0, stream>>>(scalar, WT_sc, rec_i, rec_j, N);
  k_gemm_v<<<(M + 63) / 64, 256, 0, stream>>>(vector, WT_v, rec_i, rec_j, M);
  k_edges<<<(N + 7) / 8, 512, 0, stream>>>(rec_i, rec_j, erecA, erecI, rowptr,
                                           scalar, vector, bss, bvs, bsv, bsl,
                                           Wsl2, Wv6, bc,
                                           (float*)d_out, (float*)d_out + (size_t)N * 64, N);
}

// Round 4
// 838.432 us; speedup vs baseline: 2.2637x; 1.0714x over previous
//
#include <hip/hip_runtime.h>
#include <cstdint>
#include <cstddef>

typedef unsigned int   u32;
typedef unsigned short u16;

__device__ __forceinline__ float bf2f(u32 bits16) { return __uint_as_float(bits16 << 16); }
__device__ __forceinline__ u16 f2bf(float f) {
  u32 u = __float_as_uint(f);
  u = u + 0x7FFFu + ((u >> 16) & 1u);   // round-to-nearest-even
  return (u16)(u >> 16);
}
__device__ __forceinline__ u32 pk(float a, float b) {
  return (u32)f2bf(a) | ((u32)f2bf(b) << 16);
}
__device__ __forceinline__ float lo16(u32 w) { return bf2f(w & 0xFFFFu); }
__device__ __forceinline__ float hi16(u32 w) { return bf2f(w >> 16); }
__device__ __forceinline__ float frcp(float x) { return __builtin_amdgcn_rcpf(x); }

__device__ __forceinline__ int load_idx(const int* eidx, int is64, long long pos) {
  if (is64) return (int)(((const long long*)eidx)[pos]);
  return eidx[pos];
}

// ---- weight prep (+ int32/int64 edge_index detection folded in) ----
// WT_sc[k*256+j]: j<64 a_i (Wss left), <128 a_j (Wss right), <192 c_i (Wsv left), <256 c_j (Wsv right)
// WT_v[k*128+j]:  j<64 b_i (Wvs left), <128 b_j (Wvs right)
// Wsl2[(g*64+c)*2+h] = pack(Wsl[c][4g+2h], Wsl[c][4g+2h+1]), g<32  (b64-readable pairs)
// Wv6: 3 matrices of 2048 u32 each, same pair layout with g<16:
//   m=0: Wc[c][k] (k<64), m=1: Wc[c][64+k], m=2: Wvl[c][64+k];  Wc = Wvl_left@Wvv
//   bc = Wvl_left@bvv + bvl
__global__ void k_prep_weights(const float* Wss, const float* Wvs, const float* Wsl,
                               const float* Wsv, const float* Wvv, const float* Wvl,
                               const float* bvv, const float* bvl,
                               const int* eidx, int E, int* flag,
                               float* WT_sc, float* WT_v, u32* Wsl2, u32* Wv6,
                               float* WcTmp, float* bc) {
  __shared__ int zc;
  int tid = threadIdx.x;
  if (tid == 0) zc = 0;
  __syncthreads();
  {
    int n = (E < 1024) ? E : 1024;
    int local = 0;
    for (int i = tid; i < n; i += 256) {
      if (eidx[2 * i + 1] == 0) local++;   // high words if int64 (all 0)
    }
    atomicAdd(&zc, local);
  }
  for (int o = tid; o < 64 * 256; o += 256) {
    int k = o >> 8, j = o & 255;
    float v;
    if (j < 64)       v = Wss[j * 128 + k];
    else if (j < 128) v = Wss[(j - 64) * 128 + 64 + k];
    else if (j < 192) v = Wsv[(j - 128) * 128 + k];
    else              v = Wsv[(j - 192) * 128 + 64 + k];
    WT_sc[o] = v;
  }
  for (int o = tid; o < 64 * 128; o += 256) {
    int k = o >> 7, j = o & 127;
    WT_v[o] = (j < 64) ? Wvs[j * 128 + k] : Wvs[(j - 64) * 128 + 64 + k];
  }
  for (int o = tid; o < 64 * 128; o += 256) {  // WcTmp[c*128+kk] = (Wvl_l @ Wvv)[c][kk]
    int c = o >> 7, kk = o & 127;
    float s = 0.f;
    for (int m = 0; m < 64; ++m) s += Wvl[c * 128 + m] * Wvv[m * 128 + kk];
    WcTmp[o] = s;
  }
  if (tid < 64) {
    float s = 0.f;
    for (int m = 0; m < 64; ++m) s += Wvl[tid * 128 + m] * bvv[m];
    bc[tid] = s + bvl[tid];
  }
  __syncthreads();
  if (tid == 0) {
    int n = (E < 1024) ? E : 1024;
    *flag = (zc >= (n >> 1)) ? 1 : 0;
  }
  for (int o = tid; o < 4096; o += 256) {
    int h = o & 1, c = (o >> 1) & 63, g = o >> 7;
    int k = 4 * g + 2 * h;
    Wsl2[o] = pk(Wsl[c * 128 + k], Wsl[c * 128 + k + 1]);
  }
  for (int o = tid; o < 6144; o += 256) {
    int mm = o >> 11, rem = o & 2047;
    int h = rem & 1, c = (rem >> 1) & 63, g = rem >> 7;
    int k = 4 * g + 2 * h;
    float w0, w1;
    if (mm == 0)      { w0 = WcTmp[c * 128 + k];       w1 = WcTmp[c * 128 + k + 1]; }
    else if (mm == 1) { w0 = WcTmp[c * 128 + 64 + k];  w1 = WcTmp[c * 128 + 64 + k + 1]; }
    else              { w0 = Wvl[c * 128 + 64 + k];    w1 = Wvl[c * 128 + 64 + k + 1]; }
    Wv6[o] = pk(w0, w1);
  }
}

__global__ void k_deg(const int* eidx, const int* flag, const float* attr,
                      float* deg, int* cnt, int E) {
  int e = blockIdx.x * 256 + threadIdx.x;
  if (e >= E) return;
  int is64 = *flag;
  int col = load_idx(eidx, is64, (long long)E + e);
  atomicAdd(&deg[col], attr[e]);
  atomicAdd(&cnt[col], 1);
}

__global__ void k_scan(const int* cnt, int* rowptr, int* cursor, int N, int E) {
  __shared__ int lds[1024];
  int tid = threadIdx.x;
  int CH = (N + 1023) / 1024;
  int base = tid * CH;
  int s = 0;
  for (int j = 0; j < CH; ++j) { int idx = base + j; if (idx < N) s += cnt[idx]; }
  lds[tid] = s;
  __syncthreads();
  for (int off = 1; off < 1024; off <<= 1) {
    int v = (tid >= off) ? lds[tid - off] : 0;
    __syncthreads();
    lds[tid] += v;
    __syncthreads();
  }
  int pre = (tid == 0) ? 0 : lds[tid - 1];
  for (int j = 0; j < CH; ++j) {
    int idx = base + j;
    if (idx < N) { rowptr[idx] = pre; cursor[idx] = pre; pre += cnt[idx]; }
  }
  if (tid == 0) rowptr[N] = E;
}

// CSR fill: erecA[p]={norm, dx, dy, dz} (d = pos_i - pos_j), erecI[p]=row
// dis computed inline from deg (k_dis removed)
__global__ void k_fill(const int* eidx, const int* flag, const float* attr, const float* deg,
                       const float* pos, int* cursor, float4* erecA, int* erecI, int E) {
  int e = blockIdx.x * 256 + threadIdx.x;
  if (e >= E) return;
  int is64 = *flag;
  int r  = load_idx(eidx, is64, e);
  int cl = load_idx(eidx, is64, (long long)E + e);
  float dr = deg[r], dc = deg[cl];
  float disr = (dr > 0.f) ? rsqrtf(dr) : 0.f;
  float disc = (dc > 0.f) ? rsqrtf(dc) : 0.f;
  float nrm = disr * disc * attr[e];
  float dx = pos[cl * 3 + 0] - pos[r * 3 + 0];
  float dy = pos[cl * 3 + 1] - pos[r * 3 + 1];
  float dz = pos[cl * 3 + 2] - pos[r * 3 + 2];
  int p = atomicAdd(&cursor[cl], 1);
  erecA[p] = make_float4(nrm, dx, dy, dz);
  erecI[p] = r;
}

// node GEMM: [N,64] @ WT[64,256] -> bf16 records, packed u32 (a,c) stores.
// rec_i[n]: 512 u16, granule c*8: {a_i, c_i, b_i0, b_i1, b_i2, pad, pad, pad}
// rec_j[n]: 512 u16, granule c*8: {a_j, c_j, b_j0, b_j1, b_j2, v_j0, v_j1, v_j2}
// word view: word c*4+0 = (a,c) -> written here as one u32
__global__ void k_gemm_sc(const float* X, const float* WT, u32* rec_iw, u32* rec_jw, int N) {
  __shared__ float Xs[64 * 68];
  __shared__ float Ws[64 * 68];
  int tid = threadIdx.x;
  int nb = blockIdx.x * 64;
  for (int i = 0; i < 16; ++i) {
    int flat = tid + i * 256;
    int r = flat >> 6, k = flat & 63;
    Xs[k * 68 + r] = (nb + r < N) ? X[(size_t)(nb + r) * 64 + k] : 0.f;
  }
  int ty = tid >> 4, tx = tid & 15;
  int r0 = ty * 4, c0 = tx * 4;
  float accA[4][4];
  const int order[4] = {0, 2, 1, 3};   // a_i, c_i, a_j, c_j
  for (int t = 0; t < 4; ++t) {
    int jt = order[t];
    __syncthreads();
    for (int i = 0; i < 16; ++i) {
      int flat = tid + i * 256;
      int k = flat >> 6, c = flat & 63;
      Ws[k * 68 + c] = WT[k * 256 + jt * 64 + c];
    }
    __syncthreads();
    float acc[4][4] = {};
    for (int k = 0; k < 64; ++k) {
      float4 a = *(const float4*)&Xs[k * 68 + r0];
      float4 b = *(const float4*)&Ws[k * 68 + c0];
      acc[0][0] += a.x * b.x; acc[0][1] += a.x * b.y; acc[0][2] += a.x * b.z; acc[0][3] += a.x * b.w;
      acc[1][0] += a.y * b.x; acc[1][1] += a.y * b.y; acc[1][2] += a.y * b.z; acc[1][3] += a.y * b.w;
      acc[2][0] += a.z * b.x; acc[2][1] += a.z * b.y; acc[2][2] += a.z * b.z; acc[2][3] += a.z * b.w;
      acc[3][0] += a.w * b.x; acc[3][1] += a.w * b.y; acc[3][2] += a.w * b.z; acc[3][3] += a.w * b.w;
    }
    if (t == 0 || t == 2) {
      for (int ii = 0; ii < 4; ++ii)
        for (int jj = 0; jj < 4; ++jj) accA[ii][jj] = acc[ii][jj];
    } else {
      u32* dst = (t == 1) ? rec_iw : rec_jw;
      for (int ii = 0; ii < 4; ++ii) {
        int n = nb + r0 + ii;
        if (n >= N) continue;
        for (int jj = 0; jj < 4; ++jj) {
          int cc = c0 + jj;
          dst[(size_t)n * 256 + cc * 4] = pk(accA[ii][jj], acc[ii][jj]);
        }
      }
    }
  }
}

// vector GEMM: [3N,64] @ WT[64,128] -> b_i/b_j slots; also bf16 copy of vector -> v_j slots
__global__ void k_gemm_v(const float* X, const float* WT, u16* rec_i, u16* rec_j, int M) {
  __shared__ float Xs[64 * 68];
  __shared__ float Ws[64 * 68];
  int tid = threadIdx.x;
  int mb = blockIdx.x * 64;
  for (int i = 0; i < 16; ++i) {
    int flat = tid + i * 256;
    int r = flat >> 6, k = flat & 63;
    Xs[k * 68 + r] = (mb + r < M) ? X[(size_t)(mb + r) * 64 + k] : 0.f;
  }
  __syncthreads();
  for (int i = 0; i < 16; ++i) {   // bf16 copy of vector into rec_j slots 5..7
    int flat = tid + i * 256;
    int r = flat >> 6, k = flat & 63;
    int m = mb + r;
    if (m < M) {
      int n = m / 3, d = m - n * 3;
      rec_j[(size_t)n * 512 + k * 8 + 5 + d] = f2bf(Xs[k * 68 + r]);
    }
  }
  int ty = tid >> 4, tx = tid & 15;
  int r0 = ty * 4, c0 = tx * 4;
  for (int jt = 0; jt < 2; ++jt) {
    __syncthreads();
    for (int i = 0; i < 16; ++i) {
      int flat = tid + i * 256;
      int k = flat >> 6, c = flat & 63;
      Ws[k * 68 + c] = WT[k * 128 + jt * 64 + c];
    }
    __syncthreads();
    float acc[4][4] = {};
    for (int k = 0; k < 64; ++k) {
      float4 a = *(const float4*)&Xs[k * 68 + r0];
      float4 b = *(const float4*)&Ws[k * 68 + c0];
      acc[0][0] += a.x * b.x; acc[0][1] += a.x * b.y; acc[0][2] += a.x * b.z; acc[0][3] += a.x * b.w;
      acc[1][0] += a.y * b.x; acc[1][1] += a.y * b.y; acc[1][2] += a.y * b.z; acc[1][3] += a.y * b.w;
      acc[2][0] += a.z * b.x; acc[2][1] += a.z * b.y; acc[2][2] += a.z * b.z; acc[2][3] += a.z * b.w;
      acc[3][0] += a.w * b.x; acc[3][1] += a.w * b.y; acc[3][2] += a.w * b.z; acc[3][3] += a.w * b.w;
    }
    for (int ii = 0; ii < 4; ++ii) {
      int m = mb + r0 + ii;
      if (m >= M) continue;
      int n = m / 3, d = m - n * 3;
      for (int jj = 0; jj < 4; ++jj) {
        int cc = c0 + jj;
        u16 h = f2bf(acc[ii][jj]);
        if (jt == 0) rec_i[(size_t)n * 512 + cc * 8 + 2 + d] = h;
        else         rec_j[(size_t)n * 512 + cc * 8 + 2 + d] = h;
      }
    }
  }
}

// Fused hot kernel: one wave per node. Edge metadata via wave-uniform scalar
// loads (s_load into SGPRs), gather via SGPR base + depth-2 prefetch.
__global__ __launch_bounds__(512) void k_edges(
    const u16* __restrict__ rec_i, const u16* __restrict__ rec_j,
    const float4* __restrict__ erecA, const int* __restrict__ erecI,
    const int* __restrict__ rowptr,
    const float* __restrict__ scalar, const float* __restrict__ vector,
    const float* __restrict__ bss, const float* __restrict__ bvs,
    const float* __restrict__ bsv, const float* __restrict__ bsl,
    const u32* __restrict__ Wsl2g, const u32* __restrict__ Wv6g,
    const float* __restrict__ bcg,
    float* __restrict__ out_s, float* __restrict__ out_v, int N) {
  __shared__ u32 sWsl[4096];       // 16 KB
  __shared__ u32 sWv[6144];        // 24 KB
  __shared__ float sStage[8 * 192];// 6 KB, wave-private epilogue stage
  int tid = threadIdx.x, lane = tid & 63, wv = tid >> 6;
  for (int o = tid; o < 4096; o += 512) sWsl[o] = Wsl2g[o];
  for (int o = tid; o < 6144; o += 512) sWv[o] = Wv6g[o];
  __syncthreads();   // the only block barrier

  int node = __builtin_amdgcn_readfirstlane((int)(blockIdx.x * 8) + wv);
  if (node >= N) node = N - 1;   // tail waves duplicate node N-1 (identical writes)

  uint4 riv = *(const uint4*)(rec_i + ((size_t)node << 9) + lane * 8);
  float aiB  = lo16(riv.x) + bss[lane];
  float ciB  = hi16(riv.x) + bsv[lane];
  float Bvs  = bvs[lane];
  float bib0 = lo16(riv.y) + Bvs;
  float bib1 = hi16(riv.y) + Bvs;
  float bib2 = lo16(riv.z) + Bvs;
  float bsl_c = bsl[lane], bc_c = bcg[lane];

  float us = 0, uv = 0, t0 = 0, t1 = 0, t2 = 0, g0 = 0, g1 = 0, g2 = 0, wa = 0;
  int rp = rowptr[node], re = rowptr[node + 1];
  u32 lim = (u32)(N - 1);
  const u16* rjl = rec_j + lane * 8;

  u32 rpre = min((u32)erecI[rp], lim);            // slack-allocated: erecI[E..E+63] readable
  uint4 pre = *(const uint4*)(rjl + ((size_t)rpre << 9));
  for (int p = rp; p < re; ++p) {
    uint4 cur = pre;
    u32 rn = min((u32)erecI[p + 1], lim);
    pre = *(const uint4*)(rjl + ((size_t)rn << 9));
    float4 e = erecA[p];                          // wave-uniform -> s_load_dwordx4
    float nrm = e.x, dx = e.y, dy = e.z, dz = e.w;
    float aj  = lo16(cur.x), cj  = hi16(cur.x);
    float bj0 = lo16(cur.y), bj1 = hi16(cur.y), bj2 = lo16(cur.z);
    float vj0 = hi16(cur.z), vj1 = lo16(cur.w), vj2 = hi16(cur.w);
    float xs  = aiB + aj;
    float s2s = xs * frcp(1.f + __expf(-xs));
    float y   = (bib0 + bj0) * dx;
    y = fmaf(bib1 + bj1, dy, y);
    y = fmaf(bib2 + bj2, dz, y);
    float v2s = y * frcp(1.f + __expf(-y));
    float sp2 = 2.f * (ciB + cj);
    float th0 = fmaf(-2.f, frcp(1.f + __expf(sp2 * dx)), 1.f);
    float th1 = fmaf(-2.f, frcp(1.f + __expf(sp2 * dy)), 1.f);
    float th2 = fmaf(-2.f, frcp(1.f + __expf(sp2 * dz)), 1.f);
    us = fmaf(nrm, s2s, us); uv = fmaf(nrm, v2s, uv);
    t0 = fmaf(nrm, th0, t0); t1 = fmaf(nrm, th1, t1); t2 = fmaf(nrm, th2, t2);
    g0 = fmaf(nrm, vj0, g0); g1 = fmaf(nrm, vj1, g1); g2 = fmaf(nrm, vj2, g2);
    wa += nrm;
  }

  // ---- epilogue: scalar head (wave-local, no block barrier) ----
  float* mys = &sStage[wv * 192];
  mys[lane] = us; mys[64 + lane] = uv;
  __threadfence_block();
  float acc = wa * bsl_c;
  #pragma unroll
  for (int g = 0; g < 32; ++g) {
    float4 u = *(const float4*)&mys[4 * g];
    uint2 w = *(const uint2*)&sWsl[(g * 64 + lane) * 2];
    acc = fmaf(u.x, lo16(w.x), acc);
    acc = fmaf(u.y, hi16(w.x), acc);
    acc = fmaf(u.z, lo16(w.y), acc);
    acc = fmaf(u.w, hi16(w.y), acc);
  }
  size_t so = ((size_t)node << 6) + lane;
  out_s[so] = acc * frcp(1.f + __expf(-acc)) + scalar[so];

  // ---- epilogue: vector head ----
  float gg[3] = {g0, g1, g2}, tt[3] = {t0, t1, t2};
  #pragma unroll
  for (int d = 0; d < 3; ++d) {
    size_t vo = (((size_t)node * 3 + d) << 6) + lane;
    float vid = vector[vo];
    __threadfence_block();
    mys[lane] = wa * vid; mys[64 + lane] = gg[d]; mys[128 + lane] = tt[d];
    __threadfence_block();
    float a2 = wa * bc_c;
    #pragma unroll
    for (int g = 0; g < 16; ++g) {
      float4 xu = *(const float4*)&mys[4 * g];
      float4 yu = *(const float4*)&mys[64 + 4 * g];
      float4 zu = *(const float4*)&mys[128 + 4 * g];
      int bi = (g * 64 + lane) * 2;
      uint2 wA = *(const uint2*)&sWv[bi];
      uint2 wB = *(const uint2*)&sWv[2048 + bi];
      uint2 wC = *(const uint2*)&sWv[4096 + bi];
      a2 = fmaf(xu.x, lo16(wA.x), a2); a2 = fmaf(xu.y, hi16(wA.x), a2);
      a2 = fmaf(xu.z, lo16(wA.y), a2); a2 = fmaf(xu.w, hi16(wA.y), a2);
      a2 = fmaf(yu.x, lo16(wB.x), a2); a2 = fmaf(yu.y, hi16(wB.x), a2);
      a2 = fmaf(yu.z, lo16(wB.y), a2); a2 = fmaf(yu.w, hi16(wB.y), a2);
      a2 = fmaf(zu.x, lo16(wC.x), a2); a2 = fmaf(zu.y, hi16(wC.x), a2);
      a2 = fmaf(zu.z, lo16(wC.y), a2); a2 = fmaf(zu.w, hi16(wC.y), a2);
    }
    float th = fmaf(-2.f, frcp(1.f + __expf(2.f * a2)), 1.f);
    out_v[vo] = th + vid;
  }
}

extern "C" void kernel_launch(void* const* d_in, const int* in_sizes, int n_in,
                              void* d_out, int out_size, void* d_ws, size_t ws_size,
                              hipStream_t stream) {
  const float* scalar   = (const float*)d_in[0];
  const float* vector   = (const float*)d_in[1];
  const float* position = (const float*)d_in[2];
  const int*   eidx     = (const int*)d_in[3];
  const float* attr     = (const float*)d_in[4];
  const float* Wss = (const float*)d_in[5];
  const float* bss = (const float*)d_in[6];
  const float* Wvs = (const float*)d_in[7];
  const float* bvs = (const float*)d_in[8];
  const float* Wsl = (const float*)d_in[9];
  const float* bsl = (const float*)d_in[10];
  const float* Wsv = (const float*)d_in[11];
  const float* bsv = (const float*)d_in[12];
  const float* Wvv = (const float*)d_in[13];
  const float* bvv = (const float*)d_in[14];
  const float* Wvl = (const float*)d_in[15];
  const float* bvl = (const float*)d_in[16];

  int N = in_sizes[0] / 64;
  int E = in_sizes[4];
  int M = 3 * N;

  char* wsb = (char*)d_ws;
  size_t off = 0;
  auto alloc = [&](size_t bytes) -> char* {
    char* p = wsb + off;
    off += (bytes + 255) & ~(size_t)255;
    return p;
  };
  float*  deg    = (float*)alloc((size_t)N * 4);
  int*    cnt    = (int*)alloc((size_t)N * 4);
  int*    rowptr = (int*)alloc((size_t)(N + 1) * 4);
  int*    cursor = (int*)alloc((size_t)N * 4);
  float4* erecA  = (float4*)alloc((size_t)E * 16);
  int*    erecI  = (int*)alloc((size_t)(E + 64) * 4);   // +slack for prefetch reads
  u16*    rec_i  = (u16*)alloc((size_t)N * 512 * 2);
  u16*    rec_j  = (u16*)alloc((size_t)N * 512 * 2);
  float*  WT_sc  = (float*)alloc(64 * 256 * 4);
  float*  WT_v   = (float*)alloc(64 * 128 * 4);
  u32*    Wsl2   = (u32*)alloc(4096 * 4);
  u32*    Wv6    = (u32*)alloc(6144 * 4);
  float*  WcTmp  = (float*)alloc(64 * 128 * 4);
  float*  bc     = (float*)alloc(64 * 4);
  int*    flag   = (int*)alloc(4);
  (void)ws_size; (void)n_in; (void)out_size;

  // zero deg + cnt (contiguous region)
  hipMemsetAsync(deg, 0, (size_t)((char*)rowptr - (char*)deg), stream);

  k_prep_weights<<<1, 256, 0, stream>>>(Wss, Wvs, Wsl, Wsv, Wvv, Wvl, bvv, bvl,
                                        eidx, E, flag,
                                        WT_sc, WT_v, Wsl2, Wv6, WcTmp, bc);
  k_deg<<<(E + 255) / 256, 256, 0, stream>>>(eidx, flag, attr, deg, cnt, E);
  k_scan<<<1, 1024, 0, stream>>>(cnt, rowptr, cursor, N, E);
  k_fill<<<(E + 255) / 256, 256, 0, stream>>>(eidx, flag, attr, deg, position, cursor, erecA, erecI, E);
  k_gemm_sc<<<(N + 63) / 64, 256, 0, stream>>>(scalar, WT_sc, (u32*)rec_i, (u32*)rec_j, N);
  k_gemm_v<<<(M + 63) / 64, 256, 0, stream>>>(vector, WT_v, rec_i, rec_j, M);
  k_edges<<<(N + 7) / 8, 512, 0, stream>>>(rec_i, rec_j, erecA, erecI, rowptr,
                                           scalar, vector, bss, bvs, bsv, bsl,
                                           Wsl2, Wv6, bc,
                                           (float*)d_out, (float*)d_out + (size_t)N * 64, N);
}

// Round 5
// 647.820 us; speedup vs baseline: 2.9298x; 1.2942x over previous
//
#include <hip/hip_runtime.h>
#include <cstdint>
#include <cstddef>

typedef unsigned int   u32;
typedef unsigned short u16;

__device__ __forceinline__ float bf2f(u32 bits16) { return __uint_as_float(bits16 << 16); }
__device__ __forceinline__ u16 f2bf(float f) {
  u32 u = __float_as_uint(f);
  u = u + 0x7FFFu + ((u >> 16) & 1u);   // round-to-nearest-even
  return (u16)(u >> 16);
}
__device__ __forceinline__ u32 pk(float a, float b) {
  return (u32)f2bf(a) | ((u32)f2bf(b) << 16);
}
__device__ __forceinline__ float lo16(u32 w) { return bf2f(w & 0xFFFFu); }
__device__ __forceinline__ float hi16(u32 w) { return bf2f(w >> 16); }
__device__ __forceinline__ float frcp(float x) { return __builtin_amdgcn_rcpf(x); }

__device__ __forceinline__ int load_idx(const int* eidx, int is64, long long pos) {
  if (is64) return (int)(((const long long*)eidx)[pos]);
  return eidx[pos];
}

// ---- prep stage 1 (grid 48): parallel weight transforms + edge-index width detect ----
// b 0..31 : WcTmp rows 2b,2b+1  (Wc = Wvl_left @ Wvv)
// b 32    : int64-vs-int32 detection -> flag
// b 33    : bc = Wvl_left @ bvv + bvl
// b 34..41: WT_sc slices   b 42..45: WT_v slices
__global__ void k_prep1(const float* Wss, const float* Wvs,
                        const float* Wsv, const float* Wvv, const float* Wvl,
                        const float* bvv, const float* bvl,
                        const int* eidx, int E, int* flag,
                        float* WT_sc, float* WT_v, float* WcTmp, float* bc) {
  int b = blockIdx.x, tid = threadIdx.x;
  if (b < 32) {
    int c = 2 * b + (tid >> 7), kk = tid & 127;
    float s = 0.f;
    for (int m = 0; m < 64; ++m) s += Wvl[c * 128 + m] * Wvv[m * 128 + kk];
    WcTmp[c * 128 + kk] = s;
  } else if (b == 32) {
    __shared__ int zc;
    if (tid == 0) zc = 0;
    __syncthreads();
    int n = (E < 1024) ? E : 1024;
    int local = 0;
    for (int i = tid; i < n; i += 256) {
      if (eidx[2 * i + 1] == 0) local++;   // high words if int64 (all 0)
    }
    atomicAdd(&zc, local);
    __syncthreads();
    if (tid == 0) *flag = (zc >= (n >> 1)) ? 1 : 0;
  } else if (b == 33) {
    if (tid < 64) {
      float s = 0.f;
      for (int m = 0; m < 64; ++m) s += Wvl[tid * 128 + m] * bvv[m];
      bc[tid] = s + bvl[tid];
    }
  } else if (b < 42) {
    int base = (b - 34) * 2048;
    for (int i = 0; i < 8; ++i) {
      int o = base + i * 256 + tid;
      int k = o >> 8, j = o & 255;
      float v;
      if (j < 64)       v = Wss[j * 128 + k];
      else if (j < 128) v = Wss[(j - 64) * 128 + 64 + k];
      else if (j < 192) v = Wsv[(j - 128) * 128 + k];
      else              v = Wsv[(j - 192) * 128 + 64 + k];
      WT_sc[o] = v;
    }
  } else if (b < 46) {
    int base = (b - 42) * 2048;
    for (int i = 0; i < 8; ++i) {
      int o = base + i * 256 + tid;
      int k = o >> 7, j = o & 127;
      WT_v[o] = (j < 64) ? Wvs[j * 128 + k] : Wvs[(j - 64) * 128 + 64 + k];
    }
  }
}

// ---- prep stage 2 (grid 8): pack bf16 epilogue weight tables ----
// Wsl2[(g*64+c)*2+h] = pack(Wsl[c][4g+2h], Wsl[c][4g+2h+1]), g<32
// Wv6: 3 x 2048 u32: m=0 Wc[c][k], m=1 Wc[c][64+k], m=2 Wvl[c][64+k]
__global__ void k_prep2(const float* Wsl, const float* Wvl, const float* WcTmp,
                        u32* Wsl2, u32* Wv6) {
  int b = blockIdx.x, tid = threadIdx.x;
  if (b < 2) {
    for (int i = 0; i < 8; ++i) {
      int o = b * 2048 + i * 256 + tid;
      int h = o & 1, c = (o >> 1) & 63, g = o >> 7;
      int k = 4 * g + 2 * h;
      Wsl2[o] = pk(Wsl[c * 128 + k], Wsl[c * 128 + k + 1]);
    }
  } else {
    for (int i = 0; i < 4; ++i) {
      int o = (b - 2) * 1024 + i * 256 + tid;
      int mm = o >> 11, rem = o & 2047;
      int h = rem & 1, c = (rem >> 1) & 63, g = rem >> 7;
      int k = 4 * g + 2 * h;
      float w0, w1;
      if (mm == 0)      { w0 = WcTmp[c * 128 + k];       w1 = WcTmp[c * 128 + k + 1]; }
      else if (mm == 1) { w0 = WcTmp[c * 128 + 64 + k];  w1 = WcTmp[c * 128 + 64 + k + 1]; }
      else              { w0 = Wvl[c * 128 + 64 + k];    w1 = Wvl[c * 128 + 64 + k + 1]; }
      Wv6[o] = pk(w0, w1);
    }
  }
}

__global__ void k_deg(const int* eidx, const int* flag, const float* attr,
                      float* deg, int* cnt, int E) {
  int e = blockIdx.x * 256 + threadIdx.x;
  if (e >= E) return;
  int is64 = *flag;
  int col = load_idx(eidx, is64, (long long)E + e);
  atomicAdd(&deg[col], attr[e]);
  atomicAdd(&cnt[col], 1);
}

// ---- multi-block exclusive scan of cnt -> rowptr, cursor ----
__global__ void k_scan_red(const int* cnt, int* blocksum, int N) {
  __shared__ int lds[256];
  int tid = threadIdx.x, idx = blockIdx.x * 256 + tid;
  lds[tid] = (idx < N) ? cnt[idx] : 0;
  __syncthreads();
  for (int off = 128; off > 0; off >>= 1) {
    if (tid < off) lds[tid] += lds[tid + off];
    __syncthreads();
  }
  if (tid == 0) blocksum[blockIdx.x] = lds[0];
}

__global__ void k_scan_mid(const int* blocksum, int* blockoff, int NB, int* rowptr, int N, int E) {
  __shared__ int lds[1024];
  int tid = threadIdx.x;
  int v = (tid < NB) ? blocksum[tid] : 0;
  lds[tid] = v;
  __syncthreads();
  for (int off = 1; off < 1024; off <<= 1) {
    int t = (tid >= off) ? lds[tid - off] : 0;
    __syncthreads();
    lds[tid] += t;
    __syncthreads();
  }
  if (tid < NB) blockoff[tid] = lds[tid] - v;   // exclusive
  if (tid == 0) rowptr[N] = E;
}

__global__ void k_scan_out(const int* cnt, const int* blockoff, int* rowptr, int* cursor, int N) {
  __shared__ int lds[256];
  int tid = threadIdx.x, idx = blockIdx.x * 256 + tid;
  int v = (idx < N) ? cnt[idx] : 0;
  lds[tid] = v;
  __syncthreads();
  for (int off = 1; off < 256; off <<= 1) {
    int t = (tid >= off) ? lds[tid - off] : 0;
    __syncthreads();
    lds[tid] += t;
    __syncthreads();
  }
  if (idx < N) {
    int o = blockoff[blockIdx.x] + lds[tid] - v;
    rowptr[idx] = o;
    cursor[idx] = o;
  }
}

// CSR fill: erecA[p]={norm, dx, dy, dz} (d = pos_i - pos_j), erecI[p]=row
__global__ void k_fill(const int* eidx, const int* flag, const float* attr, const float* deg,
                       const float* pos, int* cursor, float4* erecA, int* erecI, int E) {
  int e = blockIdx.x * 256 + threadIdx.x;
  if (e >= E) return;
  int is64 = *flag;
  int r  = load_idx(eidx, is64, e);
  int cl = load_idx(eidx, is64, (long long)E + e);
  float dr = deg[r], dc = deg[cl];
  float disr = (dr > 0.f) ? rsqrtf(dr) : 0.f;
  float disc = (dc > 0.f) ? rsqrtf(dc) : 0.f;
  float nrm = disr * disc * attr[e];
  float dx = pos[cl * 3 + 0] - pos[r * 3 + 0];
  float dy = pos[cl * 3 + 1] - pos[r * 3 + 1];
  float dz = pos[cl * 3 + 2] - pos[r * 3 + 2];
  int p = atomicAdd(&cursor[cl], 1);
  erecA[p] = make_float4(nrm, dx, dy, dz);
  erecI[p] = r;
}

// node GEMM: [N,64] @ WT[64,256] -> bf16 records, packed u32 (a,c) stores.
// rec_i[n]: 512 u16, granule c*8: {a_i, c_i, b_i0, b_i1, b_i2, pad, pad, pad}
// rec_j[n]: 512 u16, granule c*8: {a_j, c_j, b_j0, b_j1, b_j2, v_j0, v_j1, v_j2}
__global__ void k_gemm_sc(const float* X, const float* WT, u32* rec_iw, u32* rec_jw, int N) {
  __shared__ float Xs[64 * 68];
  __shared__ float Ws[64 * 68];
  int tid = threadIdx.x;
  int nb = blockIdx.x * 64;
  for (int i = 0; i < 16; ++i) {
    int flat = tid + i * 256;
    int r = flat >> 6, k = flat & 63;
    Xs[k * 68 + r] = (nb + r < N) ? X[(size_t)(nb + r) * 64 + k] : 0.f;
  }
  int ty = tid >> 4, tx = tid & 15;
  int r0 = ty * 4, c0 = tx * 4;
  float accA[4][4];
  const int order[4] = {0, 2, 1, 3};   // a_i, c_i, a_j, c_j
  for (int t = 0; t < 4; ++t) {
    int jt = order[t];
    __syncthreads();
    for (int i = 0; i < 16; ++i) {
      int flat = tid + i * 256;
      int k = flat >> 6, c = flat & 63;
      Ws[k * 68 + c] = WT[k * 256 + jt * 64 + c];
    }
    __syncthreads();
    float acc[4][4] = {};
    for (int k = 0; k < 64; ++k) {
      float4 a = *(const float4*)&Xs[k * 68 + r0];
      float4 b = *(const float4*)&Ws[k * 68 + c0];
      acc[0][0] += a.x * b.x; acc[0][1] += a.x * b.y; acc[0][2] += a.x * b.z; acc[0][3] += a.x * b.w;
      acc[1][0] += a.y * b.x; acc[1][1] += a.y * b.y; acc[1][2] += a.y * b.z; acc[1][3] += a.y * b.w;
      acc[2][0] += a.z * b.x; acc[2][1] += a.z * b.y; acc[2][2] += a.z * b.z; acc[2][3] += a.z * b.w;
      acc[3][0] += a.w * b.x; acc[3][1] += a.w * b.y; acc[3][2] += a.w * b.z; acc[3][3] += a.w * b.w;
    }
    if (t == 0 || t == 2) {
      for (int ii = 0; ii < 4; ++ii)
        for (int jj = 0; jj < 4; ++jj) accA[ii][jj] = acc[ii][jj];
    } else {
      u32* dst = (t == 1) ? rec_iw : rec_jw;
      for (int ii = 0; ii < 4; ++ii) {
        int n = nb + r0 + ii;
        if (n >= N) continue;
        for (int jj = 0; jj < 4; ++jj) {
          int cc = c0 + jj;
          dst[(size_t)n * 256 + cc * 4] = pk(accA[ii][jj], acc[ii][jj]);
        }
      }
    }
  }
}

// vector GEMM: [3N,64] @ WT[64,128] -> b_i/b_j slots; also bf16 copy of vector -> v_j slots
__global__ void k_gemm_v(const float* X, const float* WT, u16* rec_i, u16* rec_j, int M) {
  __shared__ float Xs[64 * 68];
  __shared__ float Ws[64 * 68];
  int tid = threadIdx.x;
  int mb = blockIdx.x * 64;
  for (int i = 0; i < 16; ++i) {
    int flat = tid + i * 256;
    int r = flat >> 6, k = flat & 63;
    Xs[k * 68 + r] = (mb + r < M) ? X[(size_t)(mb + r) * 64 + k] : 0.f;
  }
  __syncthreads();
  for (int i = 0; i < 16; ++i) {   // bf16 copy of vector into rec_j slots 5..7
    int flat = tid + i * 256;
    int r = flat >> 6, k = flat & 63;
    int m = mb + r;
    if (m < M) {
      int n = m / 3, d = m - n * 3;
      rec_j[(size_t)n * 512 + k * 8 + 5 + d] = f2bf(Xs[k * 68 + r]);
    }
  }
  int ty = tid >> 4, tx = tid & 15;
  int r0 = ty * 4, c0 = tx * 4;
  for (int jt = 0; jt < 2; ++jt) {
    __syncthreads();
    for (int i = 0; i < 16; ++i) {
      int flat = tid + i * 256;
      int k = flat >> 6, c = flat & 63;
      Ws[k * 68 + c] = WT[k * 128 + jt * 64 + c];
    }
    __syncthreads();
    float acc[4][4] = {};
    for (int k = 0; k < 64; ++k) {
      float4 a = *(const float4*)&Xs[k * 68 + r0];
      float4 b = *(const float4*)&Ws[k * 68 + c0];
      acc[0][0] += a.x * b.x; acc[0][1] += a.x * b.y; acc[0][2] += a.x * b.z; acc[0][3] += a.x * b.w;
      acc[1][0] += a.y * b.x; acc[1][1] += a.y * b.y; acc[1][2] += a.y * b.z; acc[1][3] += a.y * b.w;
      acc[2][0] += a.z * b.x; acc[2][1] += a.z * b.y; acc[2][2] += a.z * b.z; acc[2][3] += a.z * b.w;
      acc[3][0] += a.w * b.x; acc[3][1] += a.w * b.y; acc[3][2] += a.w * b.z; acc[3][3] += a.w * b.w;
    }
    for (int ii = 0; ii < 4; ++ii) {
      int m = mb + r0 + ii;
      if (m >= M) continue;
      int n = m / 3, d = m - n * 3;
      for (int jj = 0; jj < 4; ++jj) {
        int cc = c0 + jj;
        u16 h = f2bf(acc[ii][jj]);
        if (jt == 0) rec_i[(size_t)n * 512 + cc * 8 + 2 + d] = h;
        else         rec_j[(size_t)n * 512 + cc * 8 + 2 + d] = h;
      }
    }
  }
}

// Fused hot kernel: one wave per node, wave-uniform scalar edge metadata,
// 2-edge unrolled loop with double prefetch, in-wave epilogue matvecs.
__global__ __launch_bounds__(512) void k_edges(
    const u16* __restrict__ rec_i, const u16* __restrict__ rec_j,
    const float4* __restrict__ erecA, const int* __restrict__ erecI,
    const int* __restrict__ rowptr,
    const float* __restrict__ scalar, const float* __restrict__ vector,
    const float* __restrict__ bss, const float* __restrict__ bvs,
    const float* __restrict__ bsv, const float* __restrict__ bsl,
    const u32* __restrict__ Wsl2g, const u32* __restrict__ Wv6g,
    const float* __restrict__ bcg,
    float* __restrict__ out_s, float* __restrict__ out_v, int N) {
  __shared__ u32 sWsl[4096];       // 16 KB
  __shared__ u32 sWv[6144];        // 24 KB
  __shared__ float sStage[8 * 192];// 6 KB, wave-private epilogue stage
  int tid = threadIdx.x, lane = tid & 63, wv = tid >> 6;
  for (int o = tid; o < 4096; o += 512) sWsl[o] = Wsl2g[o];
  for (int o = tid; o < 6144; o += 512) sWv[o] = Wv6g[o];
  __syncthreads();   // the only block barrier

  int node = __builtin_amdgcn_readfirstlane((int)(blockIdx.x * 8) + wv);
  if (node >= N) node = N - 1;

  uint4 riv = *(const uint4*)(rec_i + ((size_t)node << 9) + lane * 8);
  float aiB  = lo16(riv.x) + bss[lane];
  float ciB  = hi16(riv.x) + bsv[lane];
  float Bvs  = bvs[lane];
  float bib0 = lo16(riv.y) + Bvs;
  float bib1 = hi16(riv.y) + Bvs;
  float bib2 = lo16(riv.z) + Bvs;
  float bsl_c = bsl[lane], bc_c = bcg[lane];

  float us = 0, uv = 0, t0 = 0, t1 = 0, t2 = 0, g0 = 0, g1 = 0, g2 = 0, wa = 0;
  int rp = rowptr[node], re = rowptr[node + 1];
  u32 lim = (u32)(N - 1);
  const u16* rjl = rec_j + lane * 8;

  // erecI has 64 ints of slack past E; poison values clamp via min()
  u32 ra = min((u32)erecI[rp], lim);
  u32 rb = min((u32)erecI[rp + 1], lim);
  uint4 pre0 = *(const uint4*)(rjl + ((size_t)ra << 9));
  uint4 pre1 = *(const uint4*)(rjl + ((size_t)rb << 9));
  int p = rp;
  #define EDGE_MATH(CUR, EV)                                                  \
    {                                                                         \
      float nrm = EV.x, dx = EV.y, dy = EV.z, dz = EV.w;                      \
      float aj  = lo16(CUR.x), cj  = hi16(CUR.x);                             \
      float bj0 = lo16(CUR.y), bj1 = hi16(CUR.y), bj2 = lo16(CUR.z);          \
      float vj0 = hi16(CUR.z), vj1 = lo16(CUR.w), vj2 = hi16(CUR.w);          \
      float xs  = aiB + aj;                                                   \
      float s2s = xs * frcp(1.f + __expf(-xs));                               \
      float y   = (bib0 + bj0) * dx;                                          \
      y = fmaf(bib1 + bj1, dy, y);                                            \
      y = fmaf(bib2 + bj2, dz, y);                                            \
      float v2s = y * frcp(1.f + __expf(-y));                                 \
      float sp2 = 2.f * (ciB + cj);                                           \
      float th0 = fmaf(-2.f, frcp(1.f + __expf(sp2 * dx)), 1.f);              \
      float th1 = fmaf(-2.f, frcp(1.f + __expf(sp2 * dy)), 1.f);              \
      float th2 = fmaf(-2.f, frcp(1.f + __expf(sp2 * dz)), 1.f);              \
      us = fmaf(nrm, s2s, us); uv = fmaf(nrm, v2s, uv);                       \
      t0 = fmaf(nrm, th0, t0); t1 = fmaf(nrm, th1, t1); t2 = fmaf(nrm, th2, t2);\
      g0 = fmaf(nrm, vj0, g0); g1 = fmaf(nrm, vj1, g1); g2 = fmaf(nrm, vj2, g2);\
      wa += nrm;                                                              \
    }
  for (; p + 1 < re; p += 2) {
    uint4 cur0 = pre0, cur1 = pre1;
    u32 rn0 = min((u32)erecI[p + 2], lim);
    u32 rn1 = min((u32)erecI[p + 3], lim);
    pre0 = *(const uint4*)(rjl + ((size_t)rn0 << 9));
    pre1 = *(const uint4*)(rjl + ((size_t)rn1 << 9));
    float4 e0 = erecA[p];
    float4 e1 = erecA[p + 1];
    EDGE_MATH(cur0, e0)
    EDGE_MATH(cur1, e1)
  }
  if (p < re) {
    uint4 cur0 = pre0;
    float4 e0 = erecA[p];
    EDGE_MATH(cur0, e0)
  }
  #undef EDGE_MATH

  // ---- epilogue: scalar head (wave-local, no block barrier) ----
  float* mys = &sStage[wv * 192];
  mys[lane] = us; mys[64 + lane] = uv;
  __threadfence_block();
  float acc = wa * bsl_c;
  #pragma unroll
  for (int g = 0; g < 32; ++g) {
    float4 u = *(const float4*)&mys[4 * g];
    uint2 w = *(const uint2*)&sWsl[(g * 64 + lane) * 2];
    acc = fmaf(u.x, lo16(w.x), acc);
    acc = fmaf(u.y, hi16(w.x), acc);
    acc = fmaf(u.z, lo16(w.y), acc);
    acc = fmaf(u.w, hi16(w.y), acc);
  }
  size_t so = ((size_t)node << 6) + lane;
  out_s[so] = acc * frcp(1.f + __expf(-acc)) + scalar[so];

  // ---- epilogue: vector head ----
  float gg[3] = {g0, g1, g2}, tt[3] = {t0, t1, t2};
  #pragma unroll
  for (int d = 0; d < 3; ++d) {
    size_t vo = (((size_t)node * 3 + d) << 6) + lane;
    float vid = vector[vo];
    __threadfence_block();
    mys[lane] = wa * vid; mys[64 + lane] = gg[d]; mys[128 + lane] = tt[d];
    __threadfence_block();
    float a2 = wa * bc_c;
    #pragma unroll
    for (int g = 0; g < 16; ++g) {
      float4 xu = *(const float4*)&mys[4 * g];
      float4 yu = *(const float4*)&mys[64 + 4 * g];
      float4 zu = *(const float4*)&mys[128 + 4 * g];
      int bi = (g * 64 + lane) * 2;
      uint2 wA = *(const uint2*)&sWv[bi];
      uint2 wB = *(const uint2*)&sWv[2048 + bi];
      uint2 wC = *(const uint2*)&sWv[4096 + bi];
      a2 = fmaf(xu.x, lo16(wA.x), a2); a2 = fmaf(xu.y, hi16(wA.x), a2);
      a2 = fmaf(xu.z, lo16(wA.y), a2); a2 = fmaf(xu.w, hi16(wA.y), a2);
      a2 = fmaf(yu.x, lo16(wB.x), a2); a2 = fmaf(yu.y, hi16(wB.x), a2);
      a2 = fmaf(yu.z, lo16(wB.y), a2); a2 = fmaf(yu.w, hi16(wB.y), a2);
      a2 = fmaf(zu.x, lo16(wC.x), a2); a2 = fmaf(zu.y, hi16(wC.x), a2);
      a2 = fmaf(zu.z, lo16(wC.y), a2); a2 = fmaf(zu.w, hi16(wC.y), a2);
    }
    float th = fmaf(-2.f, frcp(1.f + __expf(2.f * a2)), 1.f);
    out_v[vo] = th + vid;
  }
}

extern "C" void kernel_launch(void* const* d_in, const int* in_sizes, int n_in,
                              void* d_out, int out_size, void* d_ws, size_t ws_size,
                              hipStream_t stream) {
  const float* scalar   = (const float*)d_in[0];
  const float* vector   = (const float*)d_in[1];
  const float* position = (const float*)d_in[2];
  const int*   eidx     = (const int*)d_in[3];
  const float* attr     = (const float*)d_in[4];
  const float* Wss = (const float*)d_in[5];
  const float* bss = (const float*)d_in[6];
  const float* Wvs = (const float*)d_in[7];
  const float* bvs = (const float*)d_in[8];
  const float* Wsl = (const float*)d_in[9];
  const float* bsl = (const float*)d_in[10];
  const float* Wsv = (const float*)d_in[11];
  const float* bsv = (const float*)d_in[12];
  const float* Wvv = (const float*)d_in[13];
  const float* bvv = (const float*)d_in[14];
  const float* Wvl = (const float*)d_in[15];
  const float* bvl = (const float*)d_in[16];

  int N = in_sizes[0] / 64;
  int E = in_sizes[4];
  int M = 3 * N;
  int NB = (N + 255) / 256;   // scan blocks (must be <= 1024)

  char* wsb = (char*)d_ws;
  size_t off = 0;
  auto alloc = [&](size_t bytes) -> char* {
    char* p = wsb + off;
    off += (bytes + 255) & ~(size_t)255;
    return p;
  };
  float*  deg    = (float*)alloc((size_t)N * 4);
  int*    cnt    = (int*)alloc((size_t)N * 4);
  int*    rowptr = (int*)alloc((size_t)(N + 1) * 4);
  int*    cursor = (int*)alloc((size_t)N * 4);
  int*    blocksum = (int*)alloc((size_t)NB * 4);
  int*    blockoff = (int*)alloc((size_t)NB * 4);
  float4* erecA  = (float4*)alloc((size_t)E * 16);
  int*    erecI  = (int*)alloc((size_t)(E + 64) * 4);   // +slack for prefetch reads
  u16*    rec_i  = (u16*)alloc((size_t)N * 512 * 2);
  u16*    rec_j  = (u16*)alloc((size_t)N * 512 * 2);
  float*  WT_sc  = (float*)alloc(64 * 256 * 4);
  float*  WT_v   = (float*)alloc(64 * 128 * 4);
  u32*    Wsl2   = (u32*)alloc(4096 * 4);
  u32*    Wv6    = (u32*)alloc(6144 * 4);
  float*  WcTmp  = (float*)alloc(64 * 128 * 4);
  float*  bc     = (float*)alloc(64 * 4);
  int*    flag   = (int*)alloc(4);
  (void)ws_size; (void)n_in; (void)out_size;

  // zero deg + cnt (contiguous region)
  hipMemsetAsync(deg, 0, (size_t)((char*)rowptr - (char*)deg), stream);

  k_prep1<<<48, 256, 0, stream>>>(Wss, Wvs, Wsv, Wvv, Wvl, bvv, bvl,
                                  eidx, E, flag, WT_sc, WT_v, WcTmp, bc);
  k_prep2<<<8, 256, 0, stream>>>(Wsl, Wvl, WcTmp, Wsl2, Wv6);
  k_deg<<<(E + 255) / 256, 256, 0, stream>>>(eidx, flag, attr, deg, cnt, E);
  k_scan_red<<<NB, 256, 0, stream>>>(cnt, blocksum, N);
  k_scan_mid<<<1, 1024, 0, stream>>>(blocksum, blockoff, NB, rowptr, N, E);
  k_scan_out<<<NB, 256, 0, stream>>>(cnt, blockoff, rowptr, cursor, N);
  k_fill<<<(E + 255) / 256, 256, 0, stream>>>(eidx, flag, attr, deg, position, cursor, erecA, erecI, E);
  k_gemm_sc<<<(N + 63) / 64, 256, 0, stream>>>(scalar, WT_sc, (u32*)rec_i, (u32*)rec_j, N);
  k_gemm_v<<<(M + 63) / 64, 256, 0, stream>>>(vector, WT_v, rec_i, rec_j, M);
  k_edges<<<(N + 7) / 8, 512, 0, stream>>>(rec_i, rec_j, erecA, erecI, rowptr,
                                           scalar, vector, bss, bvs, bsv, bsl,
                                           Wsl2, Wv6, bc,
                                           (float*)d_out, (float*)d_out + (size_t)N * 64, N);
}